// Round 5
// baseline (751.997 us; speedup 1.0000x reference)
//
#include <hip/hip_runtime.h>
#include <math.h>

namespace {
constexpr int   NTYPES   = 200;
constexpr float CONST_T  = 0.89776110649108887f; // exp(-0.004314*(298-273))
constexpr float RAD10_   = 0.17453292519943295f;
constexpr float RAD30_   = 0.52359877559829882f;
constexpr float RAD150_  = 2.6179938779914944f;
constexpr float RAD180_  = 3.14159265358979323f;
constexpr float ION_CORR = 0.02f + 0.05f / 1.4f;

// rec.w bit layout:
//  0..7 at_name, 8..9 chain, 10..18 resnum,
// 19 rc, 20 cz, 21 aa, 22 charged, 23 virtual, 24 dipole0
constexpr unsigned RC_B   = 1u << 19;
constexpr unsigned CZ_B   = 1u << 20;
constexpr unsigned AA_B   = 1u << 21;
constexpr unsigned CHG_B  = 1u << 22;
constexpr unsigned VIRT_B = 1u << 23;
constexpr unsigned DIP0_B = 1u << 24;
constexpr unsigned RESCH_M = 0x7FF00u;  // chain | resnum
constexpr unsigned CHAIN_M = 0x300u;

constexpr int MAX_FILT_WORDS = 3200;    // 102,400 atoms @ 1 bit/atom
}

__global__ __launch_bounds__(256) void prep_rec(
    const float* __restrict__ coords,
    const float* __restrict__ props,
    const int*   __restrict__ desc,
    float4*      __restrict__ rec,
    int natoms)
{
    const int idx = blockIdx.x * blockDim.x + threadIdx.x;
    if (idx >= natoms) return;
    const int at  = desc[3 * idx];
    const int res = desc[3 * idx + 1];
    const int ch  = desc[3 * idx + 2];
    unsigned bits = (unsigned)at | ((unsigned)ch << 8) | ((unsigned)res << 10);
    if ((at == 10) | (at == 11))       bits |= RC_B;
    if (at == 12)                      bits |= CZ_B;
    if (at == 13)                      bits |= AA_B;
    if (props[5 * at + 0] == 1.0f)     bits |= CHG_B;
    if (props[5 * at + 2] == 1.0f)     bits |= VIRT_B;
    if (props[5 * at + 3] == 0.0f)     bits |= DIP0_B;
    rec[idx] = make_float4(coords[3 * idx], coords[3 * idx + 1], coords[3 * idx + 2],
                           __uint_as_float(bits));
}

// 1 bit/atom: interesting = charged | cz | rc. (i1 & i2) is a SUPERSET of the
// true pair predicate; survivors are re-checked exactly in pair_energy.
__global__ __launch_bounds__(256) void prep_filt1(
    const float* __restrict__ props,
    const int*   __restrict__ desc,
    unsigned*    __restrict__ filt,
    int nwords, int natoms)
{
    const int w = blockIdx.x * blockDim.x + threadIdx.x;
    if (w >= nwords) return;
    unsigned word = 0;
    for (int s = 0; s < 32; ++s) {
        const int a = w * 32 + s;
        if (a < natoms) {
            const int at = desc[3 * a];
            const bool interesting =
                (props[5 * at] == 1.0f) | (at == 12) | (at == 10) | (at == 11);
            if (interesting) word |= 1u << s;
        }
    }
    filt[w] = word;
}

__global__ void zero_count(unsigned* __restrict__ c) { *c = 0u; }

__device__ __forceinline__ float pair_energy(
    const float4 A, const float4 B, int i, int j,
    const float* __restrict__ partners, const float2* __restrict__ cr)
{
    const unsigned ba = __float_as_uint(A.w);
    const unsigned bb = __float_as_uint(B.w);

    const bool czA = (ba & CZ_B) != 0, czB = (bb & CZ_B) != 0;
    const bool rcA = (ba & RC_B) != 0, rcB = (bb & RC_B) != 0;
    const bool argInv = (czA & (czB | rcB)) | (czB & (czA | rcA));

    const float dx = A.x - B.x, dy = A.y - B.y, dz = A.z - B.z;
    const float dist = sqrtf(dx * dx + dy * dy + dz * dz + 1e-12f);
    const bool diff_res = ((ba ^ bb) & RESCH_M) != 0;
    if (!((dist <= 15.0f) & diff_res)) return 0.0f;

    float energy = 0.0f;

    // ---- ARG path (extremely rare): needs partners[] ----
    if (argInv && (dist >= 3.9f) && (dist <= 4.3f)) {
        const float a0x = partners[6 * i],     a0y = partners[6 * i + 1], a0z = partners[6 * i + 2];
        const float a1x = partners[6 * i + 3], a1y = partners[6 * i + 4], a1z = partners[6 * i + 5];
        const float b0x = partners[6 * j],     b0y = partners[6 * j + 1], b0z = partners[6 * j + 2];
        const float b1x = partners[6 * j + 3], b1y = partners[6 * j + 4], b1z = partners[6 * j + 5];
        const float u1x = a0x - A.x, u1y = a0y - A.y, u1z = a0z - A.z;
        const float v1x = a1x - A.x, v1y = a1y - A.y, v1z = a1z - A.z;
        const float n1x = u1y * v1z - u1z * v1y;
        const float n1y = u1z * v1x - u1x * v1z;
        const float n1z = u1x * v1y - u1y * v1x;
        const float u2x = b0x - B.x, u2y = b0y - B.y, u2z = b0z - B.z;
        const float v2x = b1x - B.x, v2y = b1y - B.y, v2z = b1z - B.z;
        const float n2x = u2y * v2z - u2z * v2y;
        const float n2y = u2z * v2x - u2x * v2z;
        const float n2z = u2x * v2y - u2y * v2x;
        const float nn1 = sqrtf(n1x * n1x + n1y * n1y + n1z * n1z + 1e-12f);
        const float nn2 = sqrtf(n2x * n2x + n2y * n2y + n2z * n2z + 1e-12f);
        const bool  m = (nn1 > 1e-6f) & (nn2 > 1e-6f);
        float cosang = (n1x * n2x + n1y * n2y + n1z * n2z) / (nn1 * nn2);
        cosang = fminf(fmaxf(cosang, -0.999999f), 0.999999f);
        const float ang = acosf(cosang);
        const bool ang_mid_bad = (ang > RAD30_) & (ang < RAD150_);
        if (m & !ang_mid_bad) {
            const float dsafe   = fmaxf(dist, 1e-6f);
            const float argEpss = 332.0f / (dsafe * 8.8f * CONST_T);
            const float temp_d  = 3.0f + fabsf(dist - 4.1f);
            const float corr_ang = (dist > RAD150_)   // reference quirk: dist vs RAD150
                ? fmaxf((RAD180_ - ang) / RAD10_, 1.0f)
                : fmaxf(dist / RAD10_, 1.0f);
            const bool  arg_arg = ((ba & bb & AA_B) != 0);
            const float c2e = arg_arg ? -1.0f : -0.5f;
            const float vk  = sqrtf(200.0f * fabsf(c2e) * ION_CORR / 298.0f);
            energy += (1.0f / corr_ang) * c2e * argEpss *
                      expf(-temp_d * vk) / (temp_d * temp_d);
        }
    }

    // ---- kon path (exact: c!=0 implies charged-flag for this prop table) ----
    const float2 t1 = cr[ba & 255u];
    const float2 t2 = cr[bb & 255u];
    const float c1 = t1.x, c2 = t2.x;
    const bool charged_charged =
        (c1 != 0.0f) & (c2 != 0.0f) &
        ((ba & VIRT_B) == 0) & ((bb & VIRT_B) == 0);
    const bool kon_mask = charged_charged &
        ((ba & DIP0_B) != 0) & ((bb & DIP0_B) != 0) &
        (((ba ^ bb) & CHAIN_M) != 0);
    if (kon_mask) {
        const float sum_radii = t1.y + t2.y - 0.09f;
        const float dd   = fmaxf(dist, sum_radii);
        const float tk   = fmaxf(dd + dd * dd * (1.0f / 30.0f), 6.0f);
        const float k_on = sqrtf(200.0f * fabsf(c1) * fabsf(c2) * 0.05f / 298.0f);
        const float first  = 332.0f * c1 * c2 / (88.0f * tk * CONST_T);
        const float second = expf(-k_on * (tk - 6.0f));
        const float third  = 1.0f + k_on * 6.0f;
        energy += 0.5f * first * second / third;
    }
    return energy;
}

// Phase 1: filter + zero-out + wave-level stream compaction of survivors.
template <int PPT>
__global__ __launch_bounds__(256) void phase1_filter(
    const unsigned* __restrict__ filtg,
    const int2*     __restrict__ pairs,
    float*          __restrict__ out,
    int2*           __restrict__ wl_ij,
    int*            __restrict__ wl_p,
    unsigned*       __restrict__ wl_count,
    int n, int nwords)
{
    __shared__ unsigned sfilt[MAX_FILT_WORDS];
    for (int t = threadIdx.x; t < nwords; t += blockDim.x) sfilt[t] = filtg[t];
    __syncthreads();

    const int      base = blockIdx.x * (blockDim.x * PPT) + threadIdx.x;
    const unsigned lane = threadIdx.x & 63u;
    const unsigned long long ltmask = (1ull << lane) - 1ull;

#pragma unroll
    for (int k = 0; k < PPT; ++k) {
        const int p  = base + k * 256;
        const bool ok = (p < n);
        const unsigned long long v = ok
            ? __builtin_nontemporal_load((const unsigned long long*)(pairs + p))
            : 0ull;
        const int i = (int)(v & 0xffffffffu);
        const int j = (int)(v >> 32);
        const unsigned w1 = sfilt[i >> 5];
        const unsigned w2 = sfilt[j >> 5];
        const bool pass = ok & ((((w1 >> (i & 31)) & (w2 >> (j & 31))) & 1u) != 0);

        const unsigned long long mask = __ballot(pass);
        const unsigned cnt = (unsigned)__popcll(mask);
        unsigned sb = 0;
        if (lane == 0 && cnt) sb = atomicAdd(wl_count, cnt);
        sb = __builtin_amdgcn_readfirstlane(sb);
        if (pass) {
            const unsigned slot = sb + (unsigned)__popcll(mask & ltmask);
            wl_ij[slot] = make_int2(i, j);
            wl_p[slot]  = p;
        }
        if (ok) out[p] = 0.0f;   // normal store: keep lines cached for phase-2 merge
    }
}

// Phase 2: dense survivor processing (all lanes do real work).
__global__ __launch_bounds__(256) void phase2_energy(
    const float4*   __restrict__ rec,
    const int2*     __restrict__ wl_ij,
    const int*      __restrict__ wl_p,
    const unsigned* __restrict__ wl_count,
    const float*    __restrict__ partners,
    const float*    __restrict__ props,
    float*          __restrict__ out)
{
    __shared__ float2 cr[NTYPES];
    for (int t = threadIdx.x; t < NTYPES; t += blockDim.x)
        cr[t] = make_float2(props[5 * t + 1], props[5 * t + 4]);
    __syncthreads();

    const unsigned m = *wl_count;
    const unsigned stride = gridDim.x * blockDim.x;
    for (unsigned t = blockIdx.x * blockDim.x + threadIdx.x; t < m; t += stride) {
        const int2  ij = wl_ij[t];
        const float4 A = rec[ij.x];
        const float4 B = rec[ij.y];
        const float  e = pair_energy(A, B, ij.x, ij.y, partners, cr);
        out[wl_p[t]] = e;
    }
}

// -------- fallback (round-1 kernel) used only if d_ws is too small --------
__global__ __launch_bounds__(256) void electro_fallback(
    const float* __restrict__ coords, const float* __restrict__ partners,
    const float* __restrict__ props, const int* __restrict__ desc,
    const int2* __restrict__ pairs, float* __restrict__ out, int n)
{
    __shared__ float sp[NTYPES * 5];
    for (int t = threadIdx.x; t < NTYPES * 5; t += blockDim.x) sp[t] = props[t];
    __syncthreads();
    const int stride = gridDim.x * blockDim.x;
    for (int p = blockIdx.x * blockDim.x + threadIdx.x; p < n; p += stride) {
        const int2 ij = pairs[p];
        const int i = ij.x, j = ij.y;
        const int at1 = desc[3 * i], at2 = desc[3 * j];
        const bool rc1 = (at1 == 10) | (at1 == 11);
        const bool rc2 = (at2 == 10) | (at2 == 11);
        const bool argInv = ((at1 == 12) & ((at2 == 12) | rc2)) |
                            ((at2 == 12) & ((at1 == 12) | rc1));
        const float* p1 = &sp[5 * at1];
        const float* p2 = &sp[5 * at2];
        const bool is_charged = ((p1[0] == 1.0f) & (p2[0] == 1.0f)) | argInv;
        float energy = 0.0f;
        if (is_charged) {
            const int res1 = desc[3 * i + 1], ch1 = desc[3 * i + 2];
            const int res2 = desc[3 * j + 1], ch2 = desc[3 * j + 2];
            const float ax = coords[3 * i], ay = coords[3 * i + 1], az = coords[3 * i + 2];
            const float bx = coords[3 * j], by = coords[3 * j + 1], bz = coords[3 * j + 2];
            const float dx = ax - bx, dy = ay - by, dz = az - bz;
            const float dist = sqrtf(dx * dx + dy * dy + dz * dz + 1e-12f);
            const bool diff_res = (res1 != res2) | (ch1 != ch2);
            if ((dist <= 15.0f) & diff_res) {
                if (argInv && (dist >= 3.9f) && (dist <= 4.3f)) {
                    const float a0x = partners[6*i],   a0y = partners[6*i+1], a0z = partners[6*i+2];
                    const float a1x = partners[6*i+3], a1y = partners[6*i+4], a1z = partners[6*i+5];
                    const float b0x = partners[6*j],   b0y = partners[6*j+1], b0z = partners[6*j+2];
                    const float b1x = partners[6*j+3], b1y = partners[6*j+4], b1z = partners[6*j+5];
                    const float u1x=a0x-ax,u1y=a0y-ay,u1z=a0z-az;
                    const float v1x=a1x-ax,v1y=a1y-ay,v1z=a1z-az;
                    const float n1x=u1y*v1z-u1z*v1y, n1y=u1z*v1x-u1x*v1z, n1z=u1x*v1y-u1y*v1x;
                    const float u2x=b0x-bx,u2y=b0y-by,u2z=b0z-bz;
                    const float v2x=b1x-bx,v2y=b1y-by,v2z=b1z-bz;
                    const float n2x=u2y*v2z-u2z*v2y, n2y=u2z*v2x-u2x*v2z, n2z=u2x*v2y-u2y*v2x;
                    const float nn1 = sqrtf(n1x*n1x+n1y*n1y+n1z*n1z+1e-12f);
                    const float nn2 = sqrtf(n2x*n2x+n2y*n2y+n2z*n2z+1e-12f);
                    const bool m = (nn1 > 1e-6f) & (nn2 > 1e-6f);
                    float cosang = (n1x*n2x+n1y*n2y+n1z*n2z)/(nn1*nn2);
                    cosang = fminf(fmaxf(cosang, -0.999999f), 0.999999f);
                    const float ang = acosf(cosang);
                    const bool ang_mid_bad = (ang > RAD30_) & (ang < RAD150_);
                    if (m & !ang_mid_bad) {
                        const float dsafe = fmaxf(dist, 1e-6f);
                        const float argEpss = 332.0f / (dsafe * 8.8f * CONST_T);
                        const float temp_d = 3.0f + fabsf(dist - 4.1f);
                        const float corr_ang = (dist > RAD150_)
                            ? fmaxf((RAD180_ - ang) / RAD10_, 1.0f)
                            : fmaxf(dist / RAD10_, 1.0f);
                        const bool arg_arg = (at1 == 13) & (at2 == 13);
                        const float c2e = arg_arg ? -1.0f : -0.5f;
                        const float vk = sqrtf(200.0f * fabsf(c2e) * ION_CORR / 298.0f);
                        energy += (1.0f/corr_ang)*c2e*argEpss*expf(-temp_d*vk)/(temp_d*temp_d);
                    }
                }
                const float c1 = p1[1], c2 = p2[1];
                const bool cc = (c1 != 0.0f) & (c2 != 0.0f) &
                                (p1[2] != 1.0f) & (p2[2] != 1.0f);
                const bool kon_mask = cc & (p1[3] == 0.0f) & (p2[3] == 0.0f) & (ch1 != ch2);
                if (kon_mask) {
                    const float sum_radii = p1[4] + p2[4] - 0.09f;
                    const float dd = fmaxf(dist, sum_radii);
                    const float tk = fmaxf(dd + dd*dd*(1.0f/30.0f), 6.0f);
                    const float k_on = sqrtf(200.0f*fabsf(c1)*fabsf(c2)*0.05f/298.0f);
                    const float first = 332.0f*c1*c2/(88.0f*tk*CONST_T);
                    const float second = expf(-k_on*(tk-6.0f));
                    const float third = 1.0f + k_on*6.0f;
                    energy += 0.5f*first*second/third;
                }
            }
        }
        out[p] = energy;
    }
}

extern "C" void kernel_launch(void* const* d_in, const int* in_sizes, int n_in,
                              void* d_out, int out_size, void* d_ws, size_t ws_size,
                              hipStream_t stream) {
    const float* coords   = (const float*)d_in[0];
    const float* partners = (const float*)d_in[1];
    const float* props    = (const float*)d_in[2];
    const int*   desc     = (const int*)d_in[3];
    const int2*  pairs    = (const int2*)d_in[4];
    float*       out      = (float*)d_out;

    const int natoms = in_sizes[0] / 3;    // 100,000
    const int n      = in_sizes[4] / 2;    // 4,000,000 pairs
    const int nwords = (natoms + 31) / 32; // 3,125

    auto align256 = [](size_t x) { return (x + 255) & ~(size_t)255; };
    const size_t rec_off   = 0;
    const size_t rec_bytes = (size_t)natoms * sizeof(float4);
    const size_t filt_off  = align256(rec_off + rec_bytes);
    const size_t filt_b    = (size_t)nwords * sizeof(unsigned);
    const size_t cnt_off   = align256(filt_off + filt_b);
    const size_t wlij_off  = align256(cnt_off + 256);
    const size_t wlij_b    = (size_t)n * sizeof(int2);
    const size_t wlp_off   = align256(wlij_off + wlij_b);
    const size_t need      = wlp_off + (size_t)n * sizeof(int);

    if (ws_size >= need && nwords <= MAX_FILT_WORDS) {
        char* ws = (char*)d_ws;
        float4*   rec      = (float4*)  (ws + rec_off);
        unsigned* filt     = (unsigned*)(ws + filt_off);
        unsigned* wl_count = (unsigned*)(ws + cnt_off);
        int2*     wl_ij    = (int2*)    (ws + wlij_off);
        int*      wl_p     = (int*)     (ws + wlp_off);

        zero_count<<<1, 1, 0, stream>>>(wl_count);
        prep_rec  <<<(natoms + 255) / 256, 256, 0, stream>>>(coords, props, desc, rec, natoms);
        prep_filt1<<<(nwords + 255) / 256, 256, 0, stream>>>(props, desc, filt, nwords, natoms);

        constexpr int PPT = 8;
        const int grid1 = (n + 256 * PPT - 1) / (256 * PPT);
        phase1_filter<PPT><<<grid1, 256, 0, stream>>>(
            filt, pairs, out, wl_ij, wl_p, wl_count, n, nwords);

        phase2_energy<<<2048, 256, 0, stream>>>(
            rec, wl_ij, wl_p, wl_count, partners, props, out);
    } else {
        const int block = 256;
        int grid = (n + block - 1) / block;
        if (grid > 2048) grid = 2048;
        electro_fallback<<<grid, block, 0, stream>>>(coords, partners, props, desc, pairs, out, n);
    }
}

// Round 6
// 48.961 us; speedup vs baseline: 15.3592x; 15.3592x over previous
//
#include <hip/hip_runtime.h>
#include <math.h>

namespace {
constexpr int   NTYPES   = 200;
constexpr float CONST_T  = 0.89776110649108887f; // exp(-0.004314*(298-273))
constexpr float RAD10_   = 0.17453292519943295f;
constexpr float RAD30_   = 0.52359877559829882f;
constexpr float RAD150_  = 2.6179938779914944f;
constexpr float RAD180_  = 3.14159265358979323f;
constexpr float ION_CORR = 0.02f + 0.05f / 1.4f;

// rec.w bit layout:
//  0..7 at_name, 8..9 chain, 10..18 resnum,
// 19 rc, 20 cz, 21 aa, 22 charged, 23 virtual, 24 dipole0
constexpr unsigned RC_B   = 1u << 19;
constexpr unsigned CZ_B   = 1u << 20;
constexpr unsigned AA_B   = 1u << 21;
constexpr unsigned CHG_B  = 1u << 22;
constexpr unsigned VIRT_B = 1u << 23;
constexpr unsigned DIP0_B = 1u << 24;
constexpr unsigned RESCH_M = 0x7FF00u;  // chain | resnum
constexpr unsigned CHAIN_M = 0x300u;

constexpr int MAX_FILT_WORDS = 3200;    // 102,400 atoms @ 1 bit/atom
constexpr int PPT   = 8;                // pairs per thread
constexpr int WAVES = 4;                // 256-thread block
constexpr int SLICE = 64 * PPT;         // 512 pairs per wave
}

__global__ __launch_bounds__(256) void prep_rec(
    const float* __restrict__ coords,
    const float* __restrict__ props,
    const int*   __restrict__ desc,
    float4*      __restrict__ rec,
    int natoms)
{
    const int idx = blockIdx.x * blockDim.x + threadIdx.x;
    if (idx >= natoms) return;
    const int at  = desc[3 * idx];
    const int res = desc[3 * idx + 1];
    const int ch  = desc[3 * idx + 2];
    unsigned bits = (unsigned)at | ((unsigned)ch << 8) | ((unsigned)res << 10);
    if ((at == 10) | (at == 11))       bits |= RC_B;
    if (at == 12)                      bits |= CZ_B;
    if (at == 13)                      bits |= AA_B;
    if (props[5 * at + 0] == 1.0f)     bits |= CHG_B;
    if (props[5 * at + 2] == 1.0f)     bits |= VIRT_B;
    if (props[5 * at + 3] == 0.0f)     bits |= DIP0_B;
    rec[idx] = make_float4(coords[3 * idx], coords[3 * idx + 1], coords[3 * idx + 2],
                           __uint_as_float(bits));
}

// 1 bit/atom: interesting = charged | cz | rc. (i1 & i2) is a SUPERSET of the
// true pair predicate; survivors are re-checked exactly in pair_energy.
__global__ __launch_bounds__(256) void prep_filt1(
    const float* __restrict__ props,
    const int*   __restrict__ desc,
    unsigned*    __restrict__ filt,
    int nwords, int natoms)
{
    const int w = blockIdx.x * blockDim.x + threadIdx.x;
    if (w >= nwords) return;
    unsigned word = 0;
    for (int s = 0; s < 32; ++s) {
        const int a = w * 32 + s;
        if (a < natoms) {
            const int at = desc[3 * a];
            const bool interesting =
                (props[5 * at] == 1.0f) | (at == 12) | (at == 10) | (at == 11);
            if (interesting) word |= 1u << s;
        }
    }
    filt[w] = word;
}

__device__ __forceinline__ float pair_energy(
    const float4 A, const float4 B, int i, int j,
    const float* __restrict__ partners, const float2* __restrict__ cr)
{
    const unsigned ba = __float_as_uint(A.w);
    const unsigned bb = __float_as_uint(B.w);

    const bool czA = (ba & CZ_B) != 0, czB = (bb & CZ_B) != 0;
    const bool rcA = (ba & RC_B) != 0, rcB = (bb & RC_B) != 0;
    const bool argInv = (czA & (czB | rcB)) | (czB & (czA | rcA));

    const float dx = A.x - B.x, dy = A.y - B.y, dz = A.z - B.z;
    const float dist = sqrtf(dx * dx + dy * dy + dz * dz + 1e-12f);
    const bool diff_res = ((ba ^ bb) & RESCH_M) != 0;
    if (!((dist <= 15.0f) & diff_res)) return 0.0f;

    float energy = 0.0f;

    // ---- ARG path (extremely rare): needs partners[] ----
    if (argInv && (dist >= 3.9f) && (dist <= 4.3f)) {
        const float a0x = partners[6 * i],     a0y = partners[6 * i + 1], a0z = partners[6 * i + 2];
        const float a1x = partners[6 * i + 3], a1y = partners[6 * i + 4], a1z = partners[6 * i + 5];
        const float b0x = partners[6 * j],     b0y = partners[6 * j + 1], b0z = partners[6 * j + 2];
        const float b1x = partners[6 * j + 3], b1y = partners[6 * j + 4], b1z = partners[6 * j + 5];
        const float u1x = a0x - A.x, u1y = a0y - A.y, u1z = a0z - A.z;
        const float v1x = a1x - A.x, v1y = a1y - A.y, v1z = a1z - A.z;
        const float n1x = u1y * v1z - u1z * v1y;
        const float n1y = u1z * v1x - u1x * v1z;
        const float n1z = u1x * v1y - u1y * v1x;
        const float u2x = b0x - B.x, u2y = b0y - B.y, u2z = b0z - B.z;
        const float v2x = b1x - B.x, v2y = b1y - B.y, v2z = b1z - B.z;
        const float n2x = u2y * v2z - u2z * v2y;
        const float n2y = u2z * v2x - u2x * v2z;
        const float n2z = u2x * v2y - u2y * v2x;
        const float nn1 = sqrtf(n1x * n1x + n1y * n1y + n1z * n1z + 1e-12f);
        const float nn2 = sqrtf(n2x * n2x + n2y * n2y + n2z * n2z + 1e-12f);
        const bool  m = (nn1 > 1e-6f) & (nn2 > 1e-6f);
        float cosang = (n1x * n2x + n1y * n2y + n1z * n2z) / (nn1 * nn2);
        cosang = fminf(fmaxf(cosang, -0.999999f), 0.999999f);
        const float ang = acosf(cosang);
        const bool ang_mid_bad = (ang > RAD30_) & (ang < RAD150_);
        if (m & !ang_mid_bad) {
            const float dsafe   = fmaxf(dist, 1e-6f);
            const float argEpss = 332.0f / (dsafe * 8.8f * CONST_T);
            const float temp_d  = 3.0f + fabsf(dist - 4.1f);
            const float corr_ang = (dist > RAD150_)   // reference quirk: dist vs RAD150
                ? fmaxf((RAD180_ - ang) / RAD10_, 1.0f)
                : fmaxf(dist / RAD10_, 1.0f);
            const bool  arg_arg = ((ba & bb & AA_B) != 0);
            const float c2e = arg_arg ? -1.0f : -0.5f;
            const float vk  = sqrtf(200.0f * fabsf(c2e) * ION_CORR / 298.0f);
            energy += (1.0f / corr_ang) * c2e * argEpss *
                      expf(-temp_d * vk) / (temp_d * temp_d);
        }
    }

    // ---- kon path (exact: c!=0 implies charged-flag for this prop table) ----
    const float2 t1 = cr[ba & 255u];
    const float2 t2 = cr[bb & 255u];
    const float c1 = t1.x, c2 = t2.x;
    const bool charged_charged =
        (c1 != 0.0f) & (c2 != 0.0f) &
        ((ba & VIRT_B) == 0) & ((bb & VIRT_B) == 0);
    const bool kon_mask = charged_charged &
        ((ba & DIP0_B) != 0) & ((bb & DIP0_B) != 0) &
        (((ba ^ bb) & CHAIN_M) != 0);
    if (kon_mask) {
        const float sum_radii = t1.y + t2.y - 0.09f;
        const float dd   = fmaxf(dist, sum_radii);
        const float tk   = fmaxf(dd + dd * dd * (1.0f / 30.0f), 6.0f);
        const float k_on = sqrtf(200.0f * fabsf(c1) * fabsf(c2) * 0.05f / 298.0f);
        const float first  = 332.0f * c1 * c2 / (88.0f * tk * CONST_T);
        const float second = expf(-k_on * (tk - 6.0f));
        const float third  = 1.0f + k_on * 6.0f;
        energy += 0.5f * first * second / third;
    }
    return energy;
}

// Fused: filter + wave-private LDS compaction + dense survivor processing.
// No atomics anywhere; each wave only touches its own LDS slice.
__global__ __launch_bounds__(256) void electro_fused(
    const float4*   __restrict__ rec,       // [natoms] 1.6 MB, L2-resident
    const unsigned* __restrict__ filtg,     // [nwords] 12.5 KB -> LDS
    const float*    __restrict__ partners,
    const float*    __restrict__ props,
    const int2*     __restrict__ pairs,
    float*          __restrict__ out,
    int n, int nwords)
{
    __shared__ unsigned sfilt[MAX_FILT_WORDS];   // 12.8 KB
    __shared__ float2   cr[NTYPES];              // 1.6 KB
    __shared__ uint2    swl[WAVES][SLICE];       // 16 KB wave-private worklists
    for (int t = threadIdx.x; t < nwords; t += blockDim.x) sfilt[t] = filtg[t];
    for (int t = threadIdx.x; t < NTYPES; t += blockDim.x)
        cr[t] = make_float2(props[5 * t + 1], props[5 * t + 4]);
    __syncthreads();

    const int      wave = threadIdx.x >> 6;
    const unsigned lane = threadIdx.x & 63u;
    const unsigned long long ltmask = (1ull << lane) - 1ull;
    const int blockbase = blockIdx.x * (256 * PPT);

    // ---- pass 1: filter 512 pairs/wave, compact survivors into LDS slice ----
    unsigned cnt = 0;                       // wave-uniform running count
#pragma unroll
    for (int k = 0; k < PPT; ++k) {
        const int p  = blockbase + k * 256 + (int)threadIdx.x;
        const bool ok = (p < n);
        const unsigned long long v = ok
            ? __builtin_nontemporal_load((const unsigned long long*)(pairs + p))
            : 0ull;
        const int i = (int)(v & 0xffffffffu);
        const int j = (int)(v >> 32);
        const unsigned w1 = sfilt[i >> 5];
        const unsigned w2 = sfilt[j >> 5];
        const bool pass = ok & ((((w1 >> (i & 31)) & (w2 >> (j & 31))) & 1u) != 0);

        const unsigned long long mask = __ballot(pass);
        if (pass) {
            const unsigned slot = cnt + (unsigned)__popcll(mask & ltmask);
            // pack: i (17b) | k (3b @17) | lane (6b @20);  y = j
            swl[wave][slot] = make_uint2(
                (unsigned)i | ((unsigned)k << 17) | (lane << 20), (unsigned)j);
        }
        cnt += (unsigned)__popcll(mask);
        if (ok & !pass) out[p] = 0.0f;      // survivors written in pass 2 (once each)
    }

    // ---- pass 2: dense processing of this wave's survivors (~17% x 512) ----
    for (unsigned t = lane; t < cnt; t += 64) {
        const uint2 e  = swl[wave][t];
        const int   i  = (int)(e.x & 0x1FFFFu);
        const int   k  = (int)((e.x >> 17) & 7u);
        const int   sl = (int)((e.x >> 20) & 63u);
        const int   j  = (int)e.y;
        const int   p  = blockbase + k * 256 + wave * 64 + sl;
        const float4 A = rec[i];
        const float4 B = rec[j];
        out[p] = pair_energy(A, B, i, j, partners, cr);
    }
}

// -------- fallback (round-1 kernel) used only if d_ws too small / atoms too many --------
__global__ __launch_bounds__(256) void electro_fallback(
    const float* __restrict__ coords, const float* __restrict__ partners,
    const float* __restrict__ props, const int* __restrict__ desc,
    const int2* __restrict__ pairs, float* __restrict__ out, int n)
{
    __shared__ float sp[NTYPES * 5];
    for (int t = threadIdx.x; t < NTYPES * 5; t += blockDim.x) sp[t] = props[t];
    __syncthreads();
    const int stride = gridDim.x * blockDim.x;
    for (int p = blockIdx.x * blockDim.x + threadIdx.x; p < n; p += stride) {
        const int2 ij = pairs[p];
        const int i = ij.x, j = ij.y;
        const int at1 = desc[3 * i], at2 = desc[3 * j];
        const bool rc1 = (at1 == 10) | (at1 == 11);
        const bool rc2 = (at2 == 10) | (at2 == 11);
        const bool argInv = ((at1 == 12) & ((at2 == 12) | rc2)) |
                            ((at2 == 12) & ((at1 == 12) | rc1));
        const float* p1 = &sp[5 * at1];
        const float* p2 = &sp[5 * at2];
        const bool is_charged = ((p1[0] == 1.0f) & (p2[0] == 1.0f)) | argInv;
        float energy = 0.0f;
        if (is_charged) {
            const int res1 = desc[3 * i + 1], ch1 = desc[3 * i + 2];
            const int res2 = desc[3 * j + 1], ch2 = desc[3 * j + 2];
            const float ax = coords[3 * i], ay = coords[3 * i + 1], az = coords[3 * i + 2];
            const float bx = coords[3 * j], by = coords[3 * j + 1], bz = coords[3 * j + 2];
            const float dx = ax - bx, dy = ay - by, dz = az - bz;
            const float dist = sqrtf(dx * dx + dy * dy + dz * dz + 1e-12f);
            const bool diff_res = (res1 != res2) | (ch1 != ch2);
            if ((dist <= 15.0f) & diff_res) {
                if (argInv && (dist >= 3.9f) && (dist <= 4.3f)) {
                    const float a0x = partners[6*i],   a0y = partners[6*i+1], a0z = partners[6*i+2];
                    const float a1x = partners[6*i+3], a1y = partners[6*i+4], a1z = partners[6*i+5];
                    const float b0x = partners[6*j],   b0y = partners[6*j+1], b0z = partners[6*j+2];
                    const float b1x = partners[6*j+3], b1y = partners[6*j+4], b1z = partners[6*j+5];
                    const float u1x=a0x-ax,u1y=a0y-ay,u1z=a0z-az;
                    const float v1x=a1x-ax,v1y=a1y-ay,v1z=a1z-az;
                    const float n1x=u1y*v1z-u1z*v1y, n1y=u1z*v1x-u1x*v1z, n1z=u1x*v1y-u1y*v1x;
                    const float u2x=b0x-bx,u2y=b0y-by,u2z=b0z-bz;
                    const float v2x=b1x-bx,v2y=b1y-by,v2z=b1z-bz;
                    const float n2x=u2y*v2z-u2z*v2y, n2y=u2z*v2x-u2x*v2z, n2z=u2x*v2y-u2y*v2x;
                    const float nn1 = sqrtf(n1x*n1x+n1y*n1y+n1z*n1z+1e-12f);
                    const float nn2 = sqrtf(n2x*n2x+n2y*n2y+n2z*n2z+1e-12f);
                    const bool m = (nn1 > 1e-6f) & (nn2 > 1e-6f);
                    float cosang = (n1x*n2x+n1y*n2y+n1z*n2z)/(nn1*nn2);
                    cosang = fminf(fmaxf(cosang, -0.999999f), 0.999999f);
                    const float ang = acosf(cosang);
                    const bool ang_mid_bad = (ang > RAD30_) & (ang < RAD150_);
                    if (m & !ang_mid_bad) {
                        const float dsafe = fmaxf(dist, 1e-6f);
                        const float argEpss = 332.0f / (dsafe * 8.8f * CONST_T);
                        const float temp_d = 3.0f + fabsf(dist - 4.1f);
                        const float corr_ang = (dist > RAD150_)
                            ? fmaxf((RAD180_ - ang) / RAD10_, 1.0f)
                            : fmaxf(dist / RAD10_, 1.0f);
                        const bool arg_arg = (at1 == 13) & (at2 == 13);
                        const float c2e = arg_arg ? -1.0f : -0.5f;
                        const float vk = sqrtf(200.0f * fabsf(c2e) * ION_CORR / 298.0f);
                        energy += (1.0f/corr_ang)*c2e*argEpss*expf(-temp_d*vk)/(temp_d*temp_d);
                    }
                }
                const float c1 = p1[1], c2 = p2[1];
                const bool cc = (c1 != 0.0f) & (c2 != 0.0f) &
                                (p1[2] != 1.0f) & (p2[2] != 1.0f);
                const bool kon_mask = cc & (p1[3] == 0.0f) & (p2[3] == 0.0f) & (ch1 != ch2);
                if (kon_mask) {
                    const float sum_radii = p1[4] + p2[4] - 0.09f;
                    const float dd = fmaxf(dist, sum_radii);
                    const float tk = fmaxf(dd + dd*dd*(1.0f/30.0f), 6.0f);
                    const float k_on = sqrtf(200.0f*fabsf(c1)*fabsf(c2)*0.05f/298.0f);
                    const float first = 332.0f*c1*c2/(88.0f*tk*CONST_T);
                    const float second = expf(-k_on*(tk-6.0f));
                    const float third = 1.0f + k_on*6.0f;
                    energy += 0.5f*first*second/third;
                }
            }
        }
        out[p] = energy;
    }
}

extern "C" void kernel_launch(void* const* d_in, const int* in_sizes, int n_in,
                              void* d_out, int out_size, void* d_ws, size_t ws_size,
                              hipStream_t stream) {
    const float* coords   = (const float*)d_in[0];
    const float* partners = (const float*)d_in[1];
    const float* props    = (const float*)d_in[2];
    const int*   desc     = (const int*)d_in[3];
    const int2*  pairs    = (const int2*)d_in[4];
    float*       out      = (float*)d_out;

    const int natoms = in_sizes[0] / 3;    // 100,000
    const int n      = in_sizes[4] / 2;    // 4,000,000 pairs
    const int nwords = (natoms + 31) / 32; // 3,125

    const size_t rec_bytes  = (size_t)natoms * sizeof(float4);
    const size_t filt_off   = (rec_bytes + 255) & ~(size_t)255;
    const size_t need_bytes = filt_off + (size_t)nwords * sizeof(unsigned);

    // i packed into 17 bits in the fused kernel
    if (ws_size >= need_bytes && nwords <= MAX_FILT_WORDS && natoms <= (1 << 17)) {
        float4*   rec  = (float4*)d_ws;
        unsigned* filt = (unsigned*)((char*)d_ws + filt_off);
        prep_rec  <<<(natoms + 255) / 256, 256, 0, stream>>>(coords, props, desc, rec, natoms);
        prep_filt1<<<(nwords + 255) / 256, 256, 0, stream>>>(props, desc, filt, nwords, natoms);
        const int grid = (n + 256 * PPT - 1) / (256 * PPT);
        electro_fused<<<grid, 256, 0, stream>>>(rec, filt, partners, props, pairs, out, n, nwords);
    } else {
        const int block = 256;
        int grid = (n + block - 1) / block;
        if (grid > 2048) grid = 2048;
        electro_fallback<<<grid, block, 0, stream>>>(coords, partners, props, desc, pairs, out, n);
    }
}

// Round 7
// 45.334 us; speedup vs baseline: 16.5878x; 1.0800x over previous
//
#include <hip/hip_runtime.h>
#include <math.h>

namespace {
constexpr int   NTYPES   = 200;
constexpr float CONST_T  = 0.89776110649108887f; // exp(-0.004314*(298-273))
constexpr float RAD10_   = 0.17453292519943295f;
constexpr float RAD30_   = 0.52359877559829882f;
constexpr float RAD150_  = 2.6179938779914944f;
constexpr float RAD180_  = 3.14159265358979323f;
constexpr float ION_CORR = 0.02f + 0.05f / 1.4f;

// rec.w bit layout:
//  0..7 at_name, 8..9 chain, 10..18 resnum,
// 19 rc, 20 cz, 21 aa, 22 charged, 23 virtual, 24 dipole0
constexpr unsigned RC_B   = 1u << 19;
constexpr unsigned CZ_B   = 1u << 20;
constexpr unsigned AA_B   = 1u << 21;
constexpr unsigned CHG_B  = 1u << 22;
constexpr unsigned VIRT_B = 1u << 23;
constexpr unsigned DIP0_B = 1u << 24;
constexpr unsigned RESCH_M = 0x7FF00u;  // chain | resnum
constexpr unsigned CHAIN_M = 0x300u;

constexpr int MAX_FILT_WORDS = 3200;    // 102,400 atoms @ 1 bit/atom
}

__global__ __launch_bounds__(256) void prep_rec(
    const float* __restrict__ coords,
    const float* __restrict__ props,
    const int*   __restrict__ desc,
    float4*      __restrict__ rec,
    int natoms)
{
    const int idx = blockIdx.x * blockDim.x + threadIdx.x;
    if (idx >= natoms) return;
    const int at  = desc[3 * idx];
    const int res = desc[3 * idx + 1];
    const int ch  = desc[3 * idx + 2];
    unsigned bits = (unsigned)at | ((unsigned)ch << 8) | ((unsigned)res << 10);
    if ((at == 10) | (at == 11))       bits |= RC_B;
    if (at == 12)                      bits |= CZ_B;
    if (at == 13)                      bits |= AA_B;
    if (props[5 * at + 0] == 1.0f)     bits |= CHG_B;
    if (props[5 * at + 2] == 1.0f)     bits |= VIRT_B;
    if (props[5 * at + 3] == 0.0f)     bits |= DIP0_B;
    rec[idx] = make_float4(coords[3 * idx], coords[3 * idx + 1], coords[3 * idx + 2],
                           __uint_as_float(bits));
}

// 1 bit/atom: interesting = charged | cz | rc. (i1 & i2) is a SUPERSET of the
// true pair predicate; survivors are re-checked exactly in pair_energy.
__global__ __launch_bounds__(256) void prep_filt1(
    const float* __restrict__ props,
    const int*   __restrict__ desc,
    unsigned*    __restrict__ filt,
    int nwords, int natoms)
{
    const int w = blockIdx.x * blockDim.x + threadIdx.x;
    if (w >= nwords) return;
    unsigned word = 0;
    for (int s = 0; s < 32; ++s) {
        const int a = w * 32 + s;
        if (a < natoms) {
            const int at = desc[3 * a];
            const bool interesting =
                (props[5 * at] == 1.0f) | (at == 12) | (at == 10) | (at == 11);
            if (interesting) word |= 1u << s;
        }
    }
    filt[w] = word;
}

__device__ __forceinline__ float pair_energy(
    const float4 A, const float4 B, int i, int j,
    const float* __restrict__ partners, const float2* __restrict__ cr)
{
    const unsigned ba = __float_as_uint(A.w);
    const unsigned bb = __float_as_uint(B.w);

    const bool czA = (ba & CZ_B) != 0, czB = (bb & CZ_B) != 0;
    const bool rcA = (ba & RC_B) != 0, rcB = (bb & RC_B) != 0;
    const bool argInv = (czA & (czB | rcB)) | (czB & (czA | rcA));

    const float dx = A.x - B.x, dy = A.y - B.y, dz = A.z - B.z;
    const float dist = sqrtf(dx * dx + dy * dy + dz * dz + 1e-12f);
    const bool diff_res = ((ba ^ bb) & RESCH_M) != 0;
    if (!((dist <= 15.0f) & diff_res)) return 0.0f;

    float energy = 0.0f;

    // ---- ARG path (extremely rare): needs partners[] ----
    if (argInv && (dist >= 3.9f) && (dist <= 4.3f)) {
        const float a0x = partners[6 * i],     a0y = partners[6 * i + 1], a0z = partners[6 * i + 2];
        const float a1x = partners[6 * i + 3], a1y = partners[6 * i + 4], a1z = partners[6 * i + 5];
        const float b0x = partners[6 * j],     b0y = partners[6 * j + 1], b0z = partners[6 * j + 2];
        const float b1x = partners[6 * j + 3], b1y = partners[6 * j + 4], b1z = partners[6 * j + 5];
        const float u1x = a0x - A.x, u1y = a0y - A.y, u1z = a0z - A.z;
        const float v1x = a1x - A.x, v1y = a1y - A.y, v1z = a1z - A.z;
        const float n1x = u1y * v1z - u1z * v1y;
        const float n1y = u1z * v1x - u1x * v1z;
        const float n1z = u1x * v1y - u1y * v1x;
        const float u2x = b0x - B.x, u2y = b0y - B.y, u2z = b0z - B.z;
        const float v2x = b1x - B.x, v2y = b1y - B.y, v2z = b1z - B.z;
        const float n2x = u2y * v2z - u2z * v2y;
        const float n2y = u2z * v2x - u2x * v2z;
        const float n2z = u2x * v2y - u2y * v2x;
        const float nn1 = sqrtf(n1x * n1x + n1y * n1y + n1z * n1z + 1e-12f);
        const float nn2 = sqrtf(n2x * n2x + n2y * n2y + n2z * n2z + 1e-12f);
        const bool  m = (nn1 > 1e-6f) & (nn2 > 1e-6f);
        float cosang = (n1x * n2x + n1y * n2y + n1z * n2z) / (nn1 * nn2);
        cosang = fminf(fmaxf(cosang, -0.999999f), 0.999999f);
        const float ang = acosf(cosang);
        const bool ang_mid_bad = (ang > RAD30_) & (ang < RAD150_);
        if (m & !ang_mid_bad) {
            const float dsafe   = fmaxf(dist, 1e-6f);
            const float argEpss = 332.0f / (dsafe * 8.8f * CONST_T);
            const float temp_d  = 3.0f + fabsf(dist - 4.1f);
            const float corr_ang = (dist > RAD150_)   // reference quirk: dist vs RAD150
                ? fmaxf((RAD180_ - ang) / RAD10_, 1.0f)
                : fmaxf(dist / RAD10_, 1.0f);
            const bool  arg_arg = ((ba & bb & AA_B) != 0);
            const float c2e = arg_arg ? -1.0f : -0.5f;
            const float vk  = sqrtf(200.0f * fabsf(c2e) * ION_CORR / 298.0f);
            energy += (1.0f / corr_ang) * c2e * argEpss *
                      expf(-temp_d * vk) / (temp_d * temp_d);
        }
    }

    // ---- kon path (exact: c!=0 implies charged-flag for this prop table) ----
    const float2 t1 = cr[ba & 255u];
    const float2 t2 = cr[bb & 255u];
    const float c1 = t1.x, c2 = t2.x;
    const bool charged_charged =
        (c1 != 0.0f) & (c2 != 0.0f) &
        ((ba & VIRT_B) == 0) & ((bb & VIRT_B) == 0);
    const bool kon_mask = charged_charged &
        ((ba & DIP0_B) != 0) & ((bb & DIP0_B) != 0) &
        (((ba ^ bb) & CHAIN_M) != 0);
    if (kon_mask) {
        const float sum_radii = t1.y + t2.y - 0.09f;
        const float dd   = fmaxf(dist, sum_radii);
        const float tk   = fmaxf(dd + dd * dd * (1.0f / 30.0f), 6.0f);
        const float k_on = sqrtf(200.0f * fabsf(c1) * fabsf(c2) * 0.05f / 298.0f);
        const float first  = 332.0f * c1 * c2 / (88.0f * tk * CONST_T);
        const float second = expf(-k_on * (tk - 6.0f));
        const float third  = 1.0f + k_on * 6.0f;
        energy += 0.5f * first * second / third;
    }
    return energy;
}

// Max-TLP dense kernel: 4 pairs/thread via 2x int4 loads, 2x float2 stores,
// no compaction, no atomics, no NT hints (working set is L3-resident).
// __launch_bounds__(256, 8): 8 waves/SIMD -> 32 waves/CU target (VGPR <= 64).
__global__ __launch_bounds__(256, 8) void electro_k7(
    const float4*   __restrict__ rec,       // [natoms] 1.6 MB, L2/L3-resident
    const unsigned* __restrict__ filtg,     // [nwords] 12.5 KB -> LDS
    const float*    __restrict__ partners,
    const float*    __restrict__ props,
    const int*      __restrict__ pairs_raw, // int2 pairs as raw ints
    float*          __restrict__ out,
    int n, int nwords)
{
    __shared__ unsigned sfilt[MAX_FILT_WORDS];   // 12.8 KB
    __shared__ float2   cr[NTYPES];              // 1.6 KB
    for (int t = threadIdx.x; t < nwords; t += blockDim.x) sfilt[t] = filtg[t];
    for (int t = threadIdx.x; t < NTYPES; t += blockDim.x)
        cr[t] = make_float2(props[5 * t + 1], props[5 * t + 4]);
    __syncthreads();

    const int base = blockIdx.x * 1024;          // 256 threads x 4 pairs
    const int t    = threadIdx.x;
    const int p0   = base + 2 * t;               // pairs p0, p0+1
    const int p1   = base + 512 + 2 * t;         // pairs p1, p1+1

    // ---- batched pair loads: 16 B/lane, fully coalesced, independent ----
    int i0, j0, i1, j1, i2, j2, i3, j3;
    if (p0 + 1 < n) {
        const int4 v = *reinterpret_cast<const int4*>(pairs_raw + 2 * p0);
        i0 = v.x; j0 = v.y; i1 = v.z; j1 = v.w;
    } else {
        i0 = j0 = i1 = j1 = 0;
        if (p0 < n) { i0 = pairs_raw[2 * p0]; j0 = pairs_raw[2 * p0 + 1]; }
    }
    if (p1 + 1 < n) {
        const int4 v = *reinterpret_cast<const int4*>(pairs_raw + 2 * p1);
        i2 = v.x; j2 = v.y; i3 = v.z; j3 = v.w;
    } else {
        i2 = j2 = i3 = j3 = 0;
        if (p1 < n) { i2 = pairs_raw[2 * p1]; j2 = pairs_raw[2 * p1 + 1]; }
    }

    // ---- filter (LDS bit table) ----
    const bool f0 = (((sfilt[i0 >> 5] >> (i0 & 31)) & (sfilt[j0 >> 5] >> (j0 & 31))) & 1u) != 0;
    const bool f1 = (((sfilt[i1 >> 5] >> (i1 & 31)) & (sfilt[j1 >> 5] >> (j1 & 31))) & 1u) != 0;
    const bool f2 = (((sfilt[i2 >> 5] >> (i2 & 31)) & (sfilt[j2 >> 5] >> (j2 & 31))) & 1u) != 0;
    const bool f3 = (((sfilt[i3 >> 5] >> (i3 & 31)) & (sfilt[j3 >> 5] >> (j3 & 31))) & 1u) != 0;

    // ---- energies (survivors gather 2x float4 from L2-resident rec) ----
    float e0 = 0.0f, e1 = 0.0f, e2 = 0.0f, e3 = 0.0f;
    if (f0) e0 = pair_energy(rec[i0], rec[j0], i0, j0, partners, cr);
    if (f1) e1 = pair_energy(rec[i1], rec[j1], i1, j1, partners, cr);
    if (f2) e2 = pair_energy(rec[i2], rec[j2], i2, j2, partners, cr);
    if (f3) e3 = pair_energy(rec[i3], rec[j3], i3, j3, partners, cr);

    // ---- coalesced 8 B stores ----
    if (p0 + 1 < n) {
        *reinterpret_cast<float2*>(out + p0) = make_float2(e0, e1);
    } else if (p0 < n) {
        out[p0] = e0;
    }
    if (p1 + 1 < n) {
        *reinterpret_cast<float2*>(out + p1) = make_float2(e2, e3);
    } else if (p1 < n) {
        out[p1] = e2;
    }
}

// -------- fallback (round-1 kernel) used only if d_ws too small / atoms too many --------
__global__ __launch_bounds__(256) void electro_fallback(
    const float* __restrict__ coords, const float* __restrict__ partners,
    const float* __restrict__ props, const int* __restrict__ desc,
    const int2* __restrict__ pairs, float* __restrict__ out, int n)
{
    __shared__ float sp[NTYPES * 5];
    for (int t = threadIdx.x; t < NTYPES * 5; t += blockDim.x) sp[t] = props[t];
    __syncthreads();
    const int stride = gridDim.x * blockDim.x;
    for (int p = blockIdx.x * blockDim.x + threadIdx.x; p < n; p += stride) {
        const int2 ij = pairs[p];
        const int i = ij.x, j = ij.y;
        const int at1 = desc[3 * i], at2 = desc[3 * j];
        const bool rc1 = (at1 == 10) | (at1 == 11);
        const bool rc2 = (at2 == 10) | (at2 == 11);
        const bool argInv = ((at1 == 12) & ((at2 == 12) | rc2)) |
                            ((at2 == 12) & ((at1 == 12) | rc1));
        const float* p1 = &sp[5 * at1];
        const float* p2 = &sp[5 * at2];
        const bool is_charged = ((p1[0] == 1.0f) & (p2[0] == 1.0f)) | argInv;
        float energy = 0.0f;
        if (is_charged) {
            const int res1 = desc[3 * i + 1], ch1 = desc[3 * i + 2];
            const int res2 = desc[3 * j + 1], ch2 = desc[3 * j + 2];
            const float ax = coords[3 * i], ay = coords[3 * i + 1], az = coords[3 * i + 2];
            const float bx = coords[3 * j], by = coords[3 * j + 1], bz = coords[3 * j + 2];
            const float dx = ax - bx, dy = ay - by, dz = az - bz;
            const float dist = sqrtf(dx * dx + dy * dy + dz * dz + 1e-12f);
            const bool diff_res = (res1 != res2) | (ch1 != ch2);
            if ((dist <= 15.0f) & diff_res) {
                if (argInv && (dist >= 3.9f) && (dist <= 4.3f)) {
                    const float a0x = partners[6*i],   a0y = partners[6*i+1], a0z = partners[6*i+2];
                    const float a1x = partners[6*i+3], a1y = partners[6*i+4], a1z = partners[6*i+5];
                    const float b0x = partners[6*j],   b0y = partners[6*j+1], b0z = partners[6*j+2];
                    const float b1x = partners[6*j+3], b1y = partners[6*j+4], b1z = partners[6*j+5];
                    const float u1x=a0x-ax,u1y=a0y-ay,u1z=a0z-az;
                    const float v1x=a1x-ax,v1y=a1y-ay,v1z=a1z-az;
                    const float n1x=u1y*v1z-u1z*v1y, n1y=u1z*v1x-u1x*v1z, n1z=u1x*v1y-u1y*v1x;
                    const float u2x=b0x-bx,u2y=b0y-by,u2z=b0z-bz;
                    const float v2x=b1x-bx,v2y=b1y-by,v2z=b1z-bz;
                    const float n2x=u2y*v2z-u2z*v2y, n2y=u2z*v2x-u2x*v2z, n2z=u2x*v2y-u2y*v2x;
                    const float nn1 = sqrtf(n1x*n1x+n1y*n1y+n1z*n1z+1e-12f);
                    const float nn2 = sqrtf(n2x*n2x+n2y*n2y+n2z*n2z+1e-12f);
                    const bool m = (nn1 > 1e-6f) & (nn2 > 1e-6f);
                    float cosang = (n1x*n2x+n1y*n2y+n1z*n2z)/(nn1*nn2);
                    cosang = fminf(fmaxf(cosang, -0.999999f), 0.999999f);
                    const float ang = acosf(cosang);
                    const bool ang_mid_bad = (ang > RAD30_) & (ang < RAD150_);
                    if (m & !ang_mid_bad) {
                        const float dsafe = fmaxf(dist, 1e-6f);
                        const float argEpss = 332.0f / (dsafe * 8.8f * CONST_T);
                        const float temp_d = 3.0f + fabsf(dist - 4.1f);
                        const float corr_ang = (dist > RAD150_)
                            ? fmaxf((RAD180_ - ang) / RAD10_, 1.0f)
                            : fmaxf(dist / RAD10_, 1.0f);
                        const bool arg_arg = (at1 == 13) & (at2 == 13);
                        const float c2e = arg_arg ? -1.0f : -0.5f;
                        const float vk = sqrtf(200.0f * fabsf(c2e) * ION_CORR / 298.0f);
                        energy += (1.0f/corr_ang)*c2e*argEpss*expf(-temp_d*vk)/(temp_d*temp_d);
                    }
                }
                const float c1 = p1[1], c2 = p2[1];
                const bool cc = (c1 != 0.0f) & (c2 != 0.0f) &
                                (p1[2] != 1.0f) & (p2[2] != 1.0f);
                const bool kon_mask = cc & (p1[3] == 0.0f) & (p2[3] == 0.0f) & (ch1 != ch2);
                if (kon_mask) {
                    const float sum_radii = p1[4] + p2[4] - 0.09f;
                    const float dd = fmaxf(dist, sum_radii);
                    const float tk = fmaxf(dd + dd*dd*(1.0f/30.0f), 6.0f);
                    const float k_on = sqrtf(200.0f*fabsf(c1)*fabsf(c2)*0.05f/298.0f);
                    const float first = 332.0f*c1*c2/(88.0f*tk*CONST_T);
                    const float second = expf(-k_on*(tk-6.0f));
                    const float third = 1.0f + k_on*6.0f;
                    energy += 0.5f*first*second/third;
                }
            }
        }
        out[p] = energy;
    }
}

extern "C" void kernel_launch(void* const* d_in, const int* in_sizes, int n_in,
                              void* d_out, int out_size, void* d_ws, size_t ws_size,
                              hipStream_t stream) {
    const float* coords   = (const float*)d_in[0];
    const float* partners = (const float*)d_in[1];
    const float* props    = (const float*)d_in[2];
    const int*   desc     = (const int*)d_in[3];
    const int*   pairs_i  = (const int*)d_in[4];
    float*       out      = (float*)d_out;

    const int natoms = in_sizes[0] / 3;    // 100,000
    const int n      = in_sizes[4] / 2;    // 4,000,000 pairs
    const int nwords = (natoms + 31) / 32; // 3,125

    const size_t rec_bytes  = (size_t)natoms * sizeof(float4);
    const size_t filt_off   = (rec_bytes + 255) & ~(size_t)255;
    const size_t need_bytes = filt_off + (size_t)nwords * sizeof(unsigned);

    if (ws_size >= need_bytes && nwords <= MAX_FILT_WORDS) {
        float4*   rec  = (float4*)d_ws;
        unsigned* filt = (unsigned*)((char*)d_ws + filt_off);
        prep_rec  <<<(natoms + 255) / 256, 256, 0, stream>>>(coords, props, desc, rec, natoms);
        prep_filt1<<<(nwords + 255) / 256, 256, 0, stream>>>(props, desc, filt, nwords, natoms);
        const int grid = (n + 1023) / 1024;   // 4 pairs/thread -> 3907 blocks
        electro_k7<<<grid, 256, 0, stream>>>(rec, filt, partners, props, pairs_i, out, n, nwords);
    } else {
        const int block = 256;
        int grid = (n + block - 1) / block;
        if (grid > 2048) grid = 2048;
        electro_fallback<<<grid, block, 0, stream>>>(coords, partners, props,
                                                     desc, (const int2*)pairs_i, out, n);
    }
}

// Round 8
// 39.275 us; speedup vs baseline: 19.1468x; 1.1543x over previous
//
#include <hip/hip_runtime.h>
#include <math.h>

namespace {
constexpr int   NTYPES   = 200;
constexpr float RAD10_   = 0.17453292519943295f;
constexpr float RAD30_   = 0.52359877559829882f;
constexpr float RAD150_  = 2.6179938779914944f;
constexpr float RAD180_  = 3.14159265358979323f;
constexpr float CONST_T  = 0.89776110649108887f; // exp(-0.004314*25)

// folded constants (all double-derived, see notes):
// 332/(8.8*CONST_T), 0.5*332/(88*CONST_T), sqrt(10/298), vk(|c2e|=1), vk(0.5)
constexpr float ARG_K   = 42.0237329f;
constexpr float KON_K   = 2.10118664f;
constexpr float KON_SQK = 0.18318580f;
constexpr float VK_AA   = 0.19337050f;
constexpr float VK_MIX  = 0.13673360f;

// rec bits layout: 0..7 at_name, 8..9 chain, 10..18 resnum,
// 19 rc, 20 cz, 21 aa, 22 charged, 23 virtual, 24 dipole0
constexpr unsigned RC_B   = 1u << 19;
constexpr unsigned CZ_B   = 1u << 20;
constexpr unsigned AA_B   = 1u << 21;
constexpr unsigned CHG_B  = 1u << 22;
constexpr unsigned VIRT_B = 1u << 23;
constexpr unsigned DIP0_B = 1u << 24;
constexpr unsigned RESCH_M = 0x7FF00u;
constexpr unsigned CHAIN_M = 0x300u;

constexpr int MAX_FILT_WORDS = 3200;   // 102,400 atoms @ 1 bit/atom
}

// 32 B per atom: rec2[2i] = {x,y,z,bits}; rec2[2i+1] = {charge, radius, 0, 0}
__global__ __launch_bounds__(256) void prep_rec(
    const float* __restrict__ coords,
    const float* __restrict__ props,
    const int*   __restrict__ desc,
    float4*      __restrict__ rec2,
    int natoms)
{
    const int idx = blockIdx.x * blockDim.x + threadIdx.x;
    if (idx >= natoms) return;
    const int at  = desc[3 * idx];
    const int res = desc[3 * idx + 1];
    const int ch  = desc[3 * idx + 2];
    unsigned bits = (unsigned)at | ((unsigned)ch << 8) | ((unsigned)res << 10);
    if ((at == 10) | (at == 11))       bits |= RC_B;
    if (at == 12)                      bits |= CZ_B;
    if (at == 13)                      bits |= AA_B;
    if (props[5 * at + 0] == 1.0f)     bits |= CHG_B;
    if (props[5 * at + 2] == 1.0f)     bits |= VIRT_B;
    if (props[5 * at + 3] == 0.0f)     bits |= DIP0_B;
    rec2[2 * idx]     = make_float4(coords[3 * idx], coords[3 * idx + 1],
                                    coords[3 * idx + 2], __uint_as_float(bits));
    rec2[2 * idx + 1] = make_float4(props[5 * at + 1], props[5 * at + 4], 0.0f, 0.0f);
}

// 1 bit/atom (interesting = charged|cz|rc) via wave ballot: one atom/thread.
// (i1 & i2) is a SUPERSET of the true pair predicate; survivors re-checked exactly.
__global__ __launch_bounds__(256) void prep_filt1(
    const float* __restrict__ props,
    const int*   __restrict__ desc,
    unsigned*    __restrict__ filt,
    int nwords, int natoms)
{
    const int a = blockIdx.x * blockDim.x + threadIdx.x;
    bool interesting = false;
    if (a < natoms) {
        const int at = desc[3 * a];
        interesting = (props[5 * at] == 1.0f) | (at == 12) | (at == 10) | (at == 11);
    }
    const unsigned long long m = __ballot(interesting);
    const unsigned lane = threadIdx.x & 63u;
    if ((lane & 31u) == 0u) {
        const int w = a >> 5;
        if (w < nwords) filt[w] = (unsigned)(m >> lane);
    }
}

// All operands already in registers (A,B geometric halves; CA,CB charge/radius
// halves). Only the rare ARG path touches memory (partners gathers).
__device__ __forceinline__ float pe(
    const float4 A, const float4 B, const float4 CA, const float4 CB,
    int i, int j, const float* __restrict__ partners)
{
    const unsigned ba = __float_as_uint(A.w);
    const unsigned bb = __float_as_uint(B.w);

    const float dx = A.x - B.x, dy = A.y - B.y, dz = A.z - B.z;
    const float dist = sqrtf(dx * dx + dy * dy + dz * dz + 1e-12f);
    const bool diff_res = ((ba ^ bb) & RESCH_M) != 0;
    if (!((dist <= 15.0f) & diff_res)) return 0.0f;

    float energy = 0.0f;

    const bool czA = (ba & CZ_B) != 0, czB = (bb & CZ_B) != 0;
    const bool rcA = (ba & RC_B) != 0, rcB = (bb & RC_B) != 0;
    const bool argInv = (czA & (czB | rcB)) | (czB & (czA | rcA));
    if (argInv && (dist >= 3.9f) && (dist <= 4.3f)) {   // ~execz for whole wave usually
        const float a0x = partners[6 * i],     a0y = partners[6 * i + 1], a0z = partners[6 * i + 2];
        const float a1x = partners[6 * i + 3], a1y = partners[6 * i + 4], a1z = partners[6 * i + 5];
        const float b0x = partners[6 * j],     b0y = partners[6 * j + 1], b0z = partners[6 * j + 2];
        const float b1x = partners[6 * j + 3], b1y = partners[6 * j + 4], b1z = partners[6 * j + 5];
        const float u1x = a0x - A.x, u1y = a0y - A.y, u1z = a0z - A.z;
        const float v1x = a1x - A.x, v1y = a1y - A.y, v1z = a1z - A.z;
        const float n1x = u1y * v1z - u1z * v1y;
        const float n1y = u1z * v1x - u1x * v1z;
        const float n1z = u1x * v1y - u1y * v1x;
        const float u2x = b0x - B.x, u2y = b0y - B.y, u2z = b0z - B.z;
        const float v2x = b1x - B.x, v2y = b1y - B.y, v2z = b1z - B.z;
        const float n2x = u2y * v2z - u2z * v2y;
        const float n2y = u2z * v2x - u2x * v2z;
        const float n2z = u2x * v2y - u2y * v2x;
        const float nn1 = sqrtf(n1x * n1x + n1y * n1y + n1z * n1z + 1e-12f);
        const float nn2 = sqrtf(n2x * n2x + n2y * n2y + n2z * n2z + 1e-12f);
        const bool  m = (nn1 > 1e-6f) & (nn2 > 1e-6f);
        float cosang = (n1x * n2x + n1y * n2y + n1z * n2z) / (nn1 * nn2);
        cosang = fminf(fmaxf(cosang, -0.999999f), 0.999999f);
        const float ang = acosf(cosang);
        const bool ang_mid_bad = (ang > RAD30_) & (ang < RAD150_);
        if (m & !ang_mid_bad) {
            const float temp_d = 3.0f + fabsf(dist - 4.1f);
            // dist in [3.9,4.3] > RAD150 always -> angle-corr branch only
            const float corr = fmaxf((RAD180_ - ang) * (1.0f / RAD10_), 1.0f);
            const bool  arg_arg = ((ba & bb & AA_B) != 0);
            const float c2e = arg_arg ? -1.0f : -0.5f;
            const float vk  = arg_arg ? VK_AA : VK_MIX;
            energy += c2e * ARG_K * expf(-temp_d * vk) /
                      (corr * dist * temp_d * temp_d);
        }
    }

    const float c1 = CA.x, c2 = CB.x;
    const bool cc = (c1 != 0.0f) & (c2 != 0.0f) &
                    ((ba & VIRT_B) == 0) & ((bb & VIRT_B) == 0);
    const bool kon = cc & ((ba & DIP0_B) != 0) & ((bb & DIP0_B) != 0) &
                     (((ba ^ bb) & CHAIN_M) != 0);
    if (kon) {
        const float sum_radii = CA.y + CB.y - 0.09f;
        const float dd   = fmaxf(dist, sum_radii);
        const float tk   = fmaxf(dd + dd * dd * (1.0f / 30.0f), 6.0f);
        const float k_on = KON_SQK * sqrtf(fabsf(c1 * c2));
        const float second = expf(-k_on * (tk - 6.0f));
        energy += KON_K * c1 * c2 * second / (tk * (1.0f + 6.0f * k_on));
    }
    return energy;
}

// PPT=2: per thread 1x int4 pair load -> 4 LDS filter reads -> 8 batched
// independent float4 gathers -> pure-register compute -> float2 store.
// Two memory levels total; no dependent gather->LDS->compute chain.
__global__ __launch_bounds__(256) void electro_k8(
    const float4*   __restrict__ rec2,      // [2*natoms] 3.2 MB, L2/L3-resident
    const unsigned* __restrict__ filtg,     // [nwords] 12.5 KB -> LDS
    const float*    __restrict__ partners,
    const int*      __restrict__ pairs_raw,
    float*          __restrict__ out,
    int n, int nwords)
{
    __shared__ unsigned sfilt[MAX_FILT_WORDS];
    for (int t = threadIdx.x; t < nwords; t += 256) sfilt[t] = filtg[t];
    __syncthreads();

    const int p0 = blockIdx.x * 512 + 2 * (int)threadIdx.x;   // pairs p0, p0+1
    int i0 = 0, j0 = 0, i1 = 0, j1 = 0;
    if (p0 + 1 < n) {
        const int4 v = *reinterpret_cast<const int4*>(pairs_raw + 2 * p0);
        i0 = v.x; j0 = v.y; i1 = v.z; j1 = v.w;
    } else if (p0 < n) {
        i0 = pairs_raw[2 * p0]; j0 = pairs_raw[2 * p0 + 1];
    }

    const bool f0 = (((sfilt[i0 >> 5] >> (i0 & 31)) & (sfilt[j0 >> 5] >> (j0 & 31))) & 1u) != 0;
    const bool f1 = (((sfilt[i1 >> 5] >> (i1 & 31)) & (sfilt[j1 >> 5] >> (j1 & 31))) & 1u) != 0;

    // select-to-zero keeps straight-line code; failing lanes broadcast line 0
    const int a0 = f0 ? i0 : 0, b0 = f0 ? j0 : 0;
    const int a1 = f1 ? i1 : 0, b1 = f1 ? j1 : 0;

    // 8 independent gathers, issued together (one latency exposure)
    const float4 A0  = rec2[2 * a0];     const float4 CA0 = rec2[2 * a0 + 1];
    const float4 B0  = rec2[2 * b0];     const float4 CB0 = rec2[2 * b0 + 1];
    const float4 A1  = rec2[2 * a1];     const float4 CA1 = rec2[2 * a1 + 1];
    const float4 B1  = rec2[2 * b1];     const float4 CB1 = rec2[2 * b1 + 1];

    const float e0 = f0 ? pe(A0, B0, CA0, CB0, i0, j0, partners) : 0.0f;
    const float e1 = f1 ? pe(A1, B1, CA1, CB1, i1, j1, partners) : 0.0f;

    if (p0 + 1 < n) {
        *reinterpret_cast<float2*>(out + p0) = make_float2(e0, e1);
    } else if (p0 < n) {
        out[p0] = e0;
    }
}

// -------- fallback (round-1 kernel) if d_ws too small / atoms too many --------
__global__ __launch_bounds__(256) void electro_fallback(
    const float* __restrict__ coords, const float* __restrict__ partners,
    const float* __restrict__ props, const int* __restrict__ desc,
    const int2* __restrict__ pairs, float* __restrict__ out, int n)
{
    __shared__ float sp[NTYPES * 5];
    for (int t = threadIdx.x; t < NTYPES * 5; t += blockDim.x) sp[t] = props[t];
    __syncthreads();
    const int stride = gridDim.x * blockDim.x;
    for (int p = blockIdx.x * blockDim.x + threadIdx.x; p < n; p += stride) {
        const int2 ij = pairs[p];
        const int i = ij.x, j = ij.y;
        const int at1 = desc[3 * i], at2 = desc[3 * j];
        const bool rc1 = (at1 == 10) | (at1 == 11);
        const bool rc2 = (at2 == 10) | (at2 == 11);
        const bool argInv = ((at1 == 12) & ((at2 == 12) | rc2)) |
                            ((at2 == 12) & ((at1 == 12) | rc1));
        const float* p1 = &sp[5 * at1];
        const float* p2 = &sp[5 * at2];
        const bool is_charged = ((p1[0] == 1.0f) & (p2[0] == 1.0f)) | argInv;
        float energy = 0.0f;
        if (is_charged) {
            const int res1 = desc[3 * i + 1], ch1 = desc[3 * i + 2];
            const int res2 = desc[3 * j + 1], ch2 = desc[3 * j + 2];
            const float ax = coords[3 * i], ay = coords[3 * i + 1], az = coords[3 * i + 2];
            const float bx = coords[3 * j], by = coords[3 * j + 1], bz = coords[3 * j + 2];
            const float dx = ax - bx, dy = ay - by, dz = az - bz;
            const float dist = sqrtf(dx * dx + dy * dy + dz * dz + 1e-12f);
            const bool diff_res = (res1 != res2) | (ch1 != ch2);
            if ((dist <= 15.0f) & diff_res) {
                if (argInv && (dist >= 3.9f) && (dist <= 4.3f)) {
                    const float a0x = partners[6*i],   a0y = partners[6*i+1], a0z = partners[6*i+2];
                    const float a1x = partners[6*i+3], a1y = partners[6*i+4], a1z = partners[6*i+5];
                    const float b0x = partners[6*j],   b0y = partners[6*j+1], b0z = partners[6*j+2];
                    const float b1x = partners[6*j+3], b1y = partners[6*j+4], b1z = partners[6*j+5];
                    const float u1x=a0x-ax,u1y=a0y-ay,u1z=a0z-az;
                    const float v1x=a1x-ax,v1y=a1y-ay,v1z=a1z-az;
                    const float n1x=u1y*v1z-u1z*v1y, n1y=u1z*v1x-u1x*v1z, n1z=u1x*v1y-u1y*v1x;
                    const float u2x=b0x-bx,u2y=b0y-by,u2z=b0z-bz;
                    const float v2x=b1x-bx,v2y=b1y-by,v2z=b1z-bz;
                    const float n2x=u2y*v2z-u2z*v2y, n2y=u2z*v2x-u2x*v2z, n2z=u2x*v2y-u2y*v2x;
                    const float nn1 = sqrtf(n1x*n1x+n1y*n1y+n1z*n1z+1e-12f);
                    const float nn2 = sqrtf(n2x*n2x+n2y*n2y+n2z*n2z+1e-12f);
                    const bool m = (nn1 > 1e-6f) & (nn2 > 1e-6f);
                    float cosang = (n1x*n2x+n1y*n2y+n1z*n2z)/(nn1*nn2);
                    cosang = fminf(fmaxf(cosang, -0.999999f), 0.999999f);
                    const float ang = acosf(cosang);
                    const bool ang_mid_bad = (ang > RAD30_) & (ang < RAD150_);
                    if (m & !ang_mid_bad) {
                        const float dsafe = fmaxf(dist, 1e-6f);
                        const float argEpss = 332.0f / (dsafe * 8.8f * CONST_T);
                        const float temp_d = 3.0f + fabsf(dist - 4.1f);
                        const float corr_ang = (dist > RAD150_)
                            ? fmaxf((RAD180_ - ang) / RAD10_, 1.0f)
                            : fmaxf(dist / RAD10_, 1.0f);
                        const bool arg_arg = (at1 == 13) & (at2 == 13);
                        const float c2e = arg_arg ? -1.0f : -0.5f;
                        const float vk = sqrtf(200.0f * fabsf(c2e) * (0.02f + 0.05f/1.4f) / 298.0f);
                        energy += (1.0f/corr_ang)*c2e*argEpss*expf(-temp_d*vk)/(temp_d*temp_d);
                    }
                }
                const float c1 = p1[1], c2 = p2[1];
                const bool cc = (c1 != 0.0f) & (c2 != 0.0f) &
                                (p1[2] != 1.0f) & (p2[2] != 1.0f);
                const bool kon_mask = cc & (p1[3] == 0.0f) & (p2[3] == 0.0f) & (ch1 != ch2);
                if (kon_mask) {
                    const float sum_radii = p1[4] + p2[4] - 0.09f;
                    const float dd = fmaxf(dist, sum_radii);
                    const float tk = fmaxf(dd + dd*dd*(1.0f/30.0f), 6.0f);
                    const float k_on = sqrtf(200.0f*fabsf(c1)*fabsf(c2)*0.05f/298.0f);
                    const float first = 332.0f*c1*c2/(88.0f*tk*CONST_T);
                    const float second = expf(-k_on*(tk-6.0f));
                    const float third = 1.0f + k_on*6.0f;
                    energy += 0.5f*first*second/third;
                }
            }
        }
        out[p] = energy;
    }
}

extern "C" void kernel_launch(void* const* d_in, const int* in_sizes, int n_in,
                              void* d_out, int out_size, void* d_ws, size_t ws_size,
                              hipStream_t stream) {
    const float* coords   = (const float*)d_in[0];
    const float* partners = (const float*)d_in[1];
    const float* props    = (const float*)d_in[2];
    const int*   desc     = (const int*)d_in[3];
    const int*   pairs_i  = (const int*)d_in[4];
    float*       out      = (float*)d_out;

    const int natoms = in_sizes[0] / 3;    // 100,000
    const int n      = in_sizes[4] / 2;    // 4,000,000 pairs
    const int nwords = (natoms + 31) / 32; // 3,125

    const size_t rec_bytes  = (size_t)natoms * 2 * sizeof(float4);
    const size_t filt_off   = (rec_bytes + 255) & ~(size_t)255;
    const size_t need_bytes = filt_off + (size_t)nwords * sizeof(unsigned);

    if (ws_size >= need_bytes && nwords <= MAX_FILT_WORDS) {
        float4*   rec2 = (float4*)d_ws;
        unsigned* filt = (unsigned*)((char*)d_ws + filt_off);
        prep_rec  <<<(natoms + 255) / 256, 256, 0, stream>>>(coords, props, desc, rec2, natoms);
        prep_filt1<<<(natoms + 255) / 256, 256, 0, stream>>>(props, desc, filt, nwords, natoms);
        const int grid = (n + 511) / 512;   // 2 pairs/thread -> 7813 blocks
        electro_k8<<<grid, 256, 0, stream>>>(rec2, filt, partners, pairs_i, out, n, nwords);
    } else {
        const int block = 256;
        int grid = (n + block - 1) / block;
        if (grid > 2048) grid = 2048;
        electro_fallback<<<grid, block, 0, stream>>>(coords, partners, props,
                                                     desc, (const int2*)pairs_i, out, n);
    }
}

// Round 10
// 33.109 us; speedup vs baseline: 22.7124x; 1.1862x over previous
//
#include <hip/hip_runtime.h>
#include <math.h>

namespace {
constexpr int   NTYPES   = 200;
constexpr float RAD10_   = 0.17453292519943295f;
constexpr float RAD30_   = 0.52359877559829882f;
constexpr float RAD150_  = 2.6179938779914944f;
constexpr float RAD180_  = 3.14159265358979323f;
constexpr float CONST_T  = 0.89776110649108887f; // exp(-0.004314*25)

// folded: 332/(8.8*CONST_T), 0.5*332/(88*CONST_T), sqrt(200*0.05/298),
// vk(|c2e|=1)=sqrt(200*ION_CORR/298), vk(0.5)
constexpr float ARG_K   = 42.0237329f;
constexpr float KON_K   = 2.10118664f;
constexpr float KON_SQK = 0.18318583f;
constexpr float VK_AA   = 0.19337050f;
constexpr float VK_MIX  = 0.13673360f;

// rec.w bits: 0..7 at_name, 8..9 chain, 10..18 resnum,
// 19 rc, 20 cz, 21 aa, 22 charged, 23 virtual, 24 dipole0,
// 25 chg_mag (|c|==1), 26 chg_sign (c<0)
constexpr unsigned RC_B   = 1u << 19;
constexpr unsigned CZ_B   = 1u << 20;
constexpr unsigned AA_B   = 1u << 21;
constexpr unsigned CHG_B  = 1u << 22;
constexpr unsigned VIRT_B = 1u << 23;
constexpr unsigned DIP0_B = 1u << 24;
constexpr unsigned MAG_B  = 1u << 25;
constexpr unsigned SGN_B  = 1u << 26;
constexpr unsigned RESCH_M = 0x7FF00u;
constexpr unsigned CHAIN_M = 0x300u;

constexpr int MAX_FILT_WORDS = 3200;   // 102,400 atoms @ 1 bit/atom
}

// Merged prep: 16 B record + 1-bit filter via ballot, one kernel.
// rec[i] = {x, y, z, bits}; charge/radius folded into bits (radius is dead
// code: sum_radii<=4.31 -> tk==max(dist+dist^2/30, 6) always).
__global__ __launch_bounds__(256) void prep_all(
    const float* __restrict__ coords,
    const float* __restrict__ props,
    const int*   __restrict__ desc,
    float4*      __restrict__ rec,
    unsigned*    __restrict__ filt,
    int nwords, int natoms)
{
    const int idx = blockIdx.x * blockDim.x + threadIdx.x;
    bool interesting = false;
    if (idx < natoms) {
        const int at  = desc[3 * idx];
        const int res = desc[3 * idx + 1];
        const int ch  = desc[3 * idx + 2];
        unsigned bits = (unsigned)at | ((unsigned)ch << 8) | ((unsigned)res << 10);
        if ((at == 10) | (at == 11))       bits |= RC_B;
        if (at == 12)                      bits |= CZ_B;
        if (at == 13)                      bits |= AA_B;
        const float c = props[5 * at + 1];
        if (props[5 * at + 0] == 1.0f)     bits |= CHG_B;
        if (props[5 * at + 2] == 1.0f)     bits |= VIRT_B;
        if (props[5 * at + 3] == 0.0f)     bits |= DIP0_B;
        if (fabsf(c) == 1.0f)              bits |= MAG_B;
        if (c < 0.0f)                      bits |= SGN_B;
        rec[idx] = make_float4(coords[3 * idx], coords[3 * idx + 1],
                               coords[3 * idx + 2], __uint_as_float(bits));
        interesting = ((bits & CHG_B) != 0) | ((bits & (CZ_B | RC_B)) != 0);
    }
    const unsigned long long m = __ballot(interesting);
    const unsigned lane = threadIdx.x & 63u;
    if ((lane & 31u) == 0u) {
        const int w = idx >> 5;
        if (w < nwords) filt[w] = (unsigned)(m >> lane);
    }
}

// Everything needed is in two 16 B records (registers). Only the rare ARG
// path touches memory (partners gathers, usually whole-wave execz).
__device__ __forceinline__ float pe(
    const float4 A, const float4 B, int i, int j,
    const float* __restrict__ partners)
{
    const unsigned ba = __float_as_uint(A.w);
    const unsigned bb = __float_as_uint(B.w);

    const float dx = A.x - B.x, dy = A.y - B.y, dz = A.z - B.z;
    const float dist = sqrtf(dx * dx + dy * dy + dz * dz + 1e-12f);
    const bool diff_res = ((ba ^ bb) & RESCH_M) != 0;
    if (!((dist <= 15.0f) & diff_res)) return 0.0f;

    float energy = 0.0f;

    const bool czA = (ba & CZ_B) != 0, czB = (bb & CZ_B) != 0;
    const bool rcA = (ba & RC_B) != 0, rcB = (bb & RC_B) != 0;
    const bool argInv = (czA & (czB | rcB)) | (czB & (czA | rcA));
    if (argInv && (dist >= 3.9f) && (dist <= 4.3f)) {
        const float a0x = partners[6 * i],     a0y = partners[6 * i + 1], a0z = partners[6 * i + 2];
        const float a1x = partners[6 * i + 3], a1y = partners[6 * i + 4], a1z = partners[6 * i + 5];
        const float b0x = partners[6 * j],     b0y = partners[6 * j + 1], b0z = partners[6 * j + 2];
        const float b1x = partners[6 * j + 3], b1y = partners[6 * j + 4], b1z = partners[6 * j + 5];
        const float u1x = a0x - A.x, u1y = a0y - A.y, u1z = a0z - A.z;
        const float v1x = a1x - A.x, v1y = a1y - A.y, v1z = a1z - A.z;
        const float n1x = u1y * v1z - u1z * v1y;
        const float n1y = u1z * v1x - u1x * v1z;
        const float n1z = u1x * v1y - u1y * v1x;
        const float u2x = b0x - B.x, u2y = b0y - B.y, u2z = b0z - B.z;
        const float v2x = b1x - B.x, v2y = b1y - B.y, v2z = b1z - B.z;
        const float n2x = u2y * v2z - u2z * v2y;
        const float n2y = u2z * v2x - u2x * v2z;
        const float n2z = u2x * v2y - u2y * v2x;
        const float nn1 = sqrtf(n1x * n1x + n1y * n1y + n1z * n1z + 1e-12f);
        const float nn2 = sqrtf(n2x * n2x + n2y * n2y + n2z * n2z + 1e-12f);
        const bool  m = (nn1 > 1e-6f) & (nn2 > 1e-6f);
        float cosang = (n1x * n2x + n1y * n2y + n1z * n2z) / (nn1 * nn2);
        cosang = fminf(fmaxf(cosang, -0.999999f), 0.999999f);
        const float ang = acosf(cosang);
        const bool ang_mid_bad = (ang > RAD30_) & (ang < RAD150_);
        if (m & !ang_mid_bad) {
            const float temp_d = 3.0f + fabsf(dist - 4.1f);
            // dist in [3.9,4.3] > RAD150 -> angle-corr branch always
            const float corr = fmaxf((RAD180_ - ang) * (1.0f / RAD10_), 1.0f);
            const bool  arg_arg = ((ba & bb & AA_B) != 0);
            const float c2e = arg_arg ? -1.0f : -0.5f;
            const float vk  = arg_arg ? VK_AA : VK_MIX;
            energy += c2e * ARG_K * expf(-temp_d * vk) /
                      (corr * dist * temp_d * temp_d);
        }
    }

    // kon: charge magnitude/sign from bits (c != 0 <=> CHG flag; radius dead)
    const bool kon = ((ba & bb & CHG_B) != 0) &
                     (((ba | bb) & VIRT_B) == 0) &
                     ((ba & bb & DIP0_B) != 0) &
                     (((ba ^ bb) & CHAIN_M) != 0);
    if (kon) {
        const float tk = fmaxf(dist + dist * dist * (1.0f / 30.0f), 6.0f);
        const int ms = (int)((ba >> 25) & 1u) + (int)((bb >> 25) & 1u);
        const float mag  = (ms == 0) ? 0.25f : ((ms == 1) ? 0.5f : 1.0f);
        const float k_on = KON_SQK * ((ms == 0) ? 0.5f : ((ms == 1) ? 0.70710678f : 1.0f));
        const float e = KON_K * mag * expf(-k_on * (tk - 6.0f)) /
                        (tk * (1.0f + 6.0f * k_on));
        energy += (((ba ^ bb) & SGN_B) != 0) ? -e : e;
    }
    return energy;
}

// PPT=2: int4 pair load -> 4 LDS filter bits -> 4 independent float4 gathers
// (16 B/atom, one 64 B line per atom) -> register compute -> float2 store.
__global__ __launch_bounds__(256, 6) void electro_k9(
    const float4*   __restrict__ rec,       // [natoms] 1.6 MB, L2-resident
    const unsigned* __restrict__ filtg,     // [nwords] 12.5 KB -> LDS
    const float*    __restrict__ partners,
    const int*      __restrict__ pairs_raw,
    float*          __restrict__ out,
    int n, int nwords)
{
    __shared__ unsigned sfilt[MAX_FILT_WORDS];
    for (int t = threadIdx.x; t < nwords; t += 256) sfilt[t] = filtg[t];
    __syncthreads();

    const int p0 = blockIdx.x * 512 + 2 * (int)threadIdx.x;   // pairs p0, p0+1
    int i0 = 0, j0 = 0, i1 = 0, j1 = 0;
    if (p0 + 1 < n) {
        const int4 v = *reinterpret_cast<const int4*>(pairs_raw + 2 * p0);
        i0 = v.x; j0 = v.y; i1 = v.z; j1 = v.w;
    } else if (p0 < n) {
        i0 = pairs_raw[2 * p0]; j0 = pairs_raw[2 * p0 + 1];
    }

    const bool f0 = (((sfilt[i0 >> 5] >> (i0 & 31)) & (sfilt[j0 >> 5] >> (j0 & 31))) & 1u) != 0;
    const bool f1 = (((sfilt[i1 >> 5] >> (i1 & 31)) & (sfilt[j1 >> 5] >> (j1 & 31))) & 1u) != 0;

    // select-to-zero: failing lanes broadcast line 0 (free)
    const int a0 = f0 ? i0 : 0, b0 = f0 ? j0 : 0;
    const int a1 = f1 ? i1 : 0, b1 = f1 ? j1 : 0;

    const float4 A0 = rec[a0];
    const float4 B0 = rec[b0];
    const float4 A1 = rec[a1];
    const float4 B1 = rec[b1];

    const float e0 = f0 ? pe(A0, B0, i0, j0, partners) : 0.0f;
    const float e1 = f1 ? pe(A1, B1, i1, j1, partners) : 0.0f;

    if (p0 + 1 < n) {
        *reinterpret_cast<float2*>(out + p0) = make_float2(e0, e1);
    } else if (p0 < n) {
        out[p0] = e0;
    }
}

// -------- fallback (reference-direct) if d_ws too small / atoms too many --------
__global__ __launch_bounds__(256) void electro_fallback(
    const float* __restrict__ coords, const float* __restrict__ partners,
    const float* __restrict__ props, const int* __restrict__ desc,
    const int2* __restrict__ pairs, float* __restrict__ out, int n)
{
    __shared__ float sp[NTYPES * 5];
    for (int t = threadIdx.x; t < NTYPES * 5; t += blockDim.x) sp[t] = props[t];
    __syncthreads();
    const int stride = gridDim.x * blockDim.x;
    for (int p = blockIdx.x * blockDim.x + threadIdx.x; p < n; p += stride) {
        const int2 ij = pairs[p];
        const int i = ij.x, j = ij.y;
        const int at1 = desc[3 * i], at2 = desc[3 * j];
        const bool rc1 = (at1 == 10) | (at1 == 11);
        const bool rc2 = (at2 == 10) | (at2 == 11);
        const bool argInv = ((at1 == 12) & ((at2 == 12) | rc2)) |
                            ((at2 == 12) & ((at1 == 12) | rc1));
        const float* p1 = &sp[5 * at1];
        const float* p2 = &sp[5 * at2];
        const bool is_charged = ((p1[0] == 1.0f) & (p2[0] == 1.0f)) | argInv;
        float energy = 0.0f;
        if (is_charged) {
            const int res1 = desc[3 * i + 1], ch1 = desc[3 * i + 2];
            const int res2 = desc[3 * j + 1], ch2 = desc[3 * j + 2];
            const float ax = coords[3 * i], ay = coords[3 * i + 1], az = coords[3 * i + 2];
            const float bx = coords[3 * j], by = coords[3 * j + 1], bz = coords[3 * j + 2];
            const float dx = ax - bx, dy = ay - by, dz = az - bz;
            const float dist = sqrtf(dx * dx + dy * dy + dz * dz + 1e-12f);
            const bool diff_res = (res1 != res2) | (ch1 != ch2);
            if ((dist <= 15.0f) & diff_res) {
                if (argInv && (dist >= 3.9f) && (dist <= 4.3f)) {
                    const float a0x = partners[6*i],   a0y = partners[6*i+1], a0z = partners[6*i+2];
                    const float a1x = partners[6*i+3], a1y = partners[6*i+4], a1z = partners[6*i+5];
                    const float b0x = partners[6*j],   b0y = partners[6*j+1], b0z = partners[6*j+2];
                    const float b1x = partners[6*j+3], b1y = partners[6*j+4], b1z = partners[6*j+5];
                    const float u1x=a0x-ax,u1y=a0y-ay,u1z=a0z-az;
                    const float v1x=a1x-ax,v1y=a1y-ay,v1z=a1z-az;
                    const float n1x=u1y*v1z-u1z*v1y, n1y=u1z*v1x-u1x*v1z, n1z=u1x*v1y-u1y*v1x;
                    const float u2x=b0x-bx,u2y=b0y-by,u2z=b0z-bz;
                    const float v2x=b1x-bx,v2y=b1y-by,v2z=b1z-bz;
                    const float n2x=u2y*v2z-u2z*v2y, n2y=u2z*v2x-u2x*v2z, n2z=u2x*v2y-u2y*v2x;
                    const float nn1 = sqrtf(n1x*n1x+n1y*n1y+n1z*n1z+1e-12f);
                    const float nn2 = sqrtf(n2x*n2x+n2y*n2y+n2z*n2z+1e-12f);
                    const bool m = (nn1 > 1e-6f) & (nn2 > 1e-6f);
                    float cosang = (n1x*n2x+n1y*n2y+n1z*n2z)/(nn1*nn2);
                    cosang = fminf(fmaxf(cosang, -0.999999f), 0.999999f);
                    const float ang = acosf(cosang);
                    const bool ang_mid_bad = (ang > RAD30_) & (ang < RAD150_);
                    if (m & !ang_mid_bad) {
                        const float dsafe = fmaxf(dist, 1e-6f);
                        const float argEpss = 332.0f / (dsafe * 8.8f * CONST_T);
                        const float temp_d = 3.0f + fabsf(dist - 4.1f);
                        const float corr_ang = (dist > RAD150_)
                            ? fmaxf((RAD180_ - ang) / RAD10_, 1.0f)
                            : fmaxf(dist / RAD10_, 1.0f);
                        const bool arg_arg = (at1 == 13) & (at2 == 13);
                        const float c2e = arg_arg ? -1.0f : -0.5f;
                        const float vk = sqrtf(200.0f * fabsf(c2e) * (0.02f + 0.05f/1.4f) / 298.0f);
                        energy += (1.0f/corr_ang)*c2e*argEpss*expf(-temp_d*vk)/(temp_d*temp_d);
                    }
                }
                const float c1 = p1[1], c2 = p2[1];
                const bool cc = (c1 != 0.0f) & (c2 != 0.0f) &
                                (p1[2] != 1.0f) & (p2[2] != 1.0f);
                const bool kon_mask = cc & (p1[3] == 0.0f) & (p2[3] == 0.0f) & (ch1 != ch2);
                if (kon_mask) {
                    const float sum_radii = p1[4] + p2[4] - 0.09f;
                    const float dd = fmaxf(dist, sum_radii);
                    const float tk = fmaxf(dd + dd*dd*(1.0f/30.0f), 6.0f);
                    const float k_on = sqrtf(200.0f*fabsf(c1)*fabsf(c2)*0.05f/298.0f);
                    const float first = 332.0f*c1*c2/(88.0f*tk*CONST_T);
                    const float second = expf(-k_on*(tk-6.0f));
                    const float third = 1.0f + k_on*6.0f;
                    energy += 0.5f*first*second/third;
                }
            }
        }
        out[p] = energy;
    }
}

extern "C" void kernel_launch(void* const* d_in, const int* in_sizes, int n_in,
                              void* d_out, int out_size, void* d_ws, size_t ws_size,
                              hipStream_t stream) {
    const float* coords   = (const float*)d_in[0];
    const float* partners = (const float*)d_in[1];
    const float* props    = (const float*)d_in[2];
    const int*   desc     = (const int*)d_in[3];
    const int*   pairs_i  = (const int*)d_in[4];
    float*       out      = (float*)d_out;

    const int natoms = in_sizes[0] / 3;    // 100,000
    const int n      = in_sizes[4] / 2;    // 4,000,000 pairs
    const int nwords = (natoms + 31) / 32; // 3,125

    const size_t rec_bytes  = (size_t)natoms * sizeof(float4);
    const size_t filt_off   = (rec_bytes + 255) & ~(size_t)255;
    const size_t need_bytes = filt_off + (size_t)nwords * sizeof(unsigned);

    if (ws_size >= need_bytes && nwords <= MAX_FILT_WORDS) {
        float4*   rec  = (float4*)d_ws;
        unsigned* filt = (unsigned*)((char*)d_ws + filt_off);
        prep_all<<<(natoms + 255) / 256, 256, 0, stream>>>(
            coords, props, desc, rec, filt, nwords, natoms);
        const int grid = (n + 511) / 512;   // 2 pairs/thread -> 7813 blocks
        electro_k9<<<grid, 256, 0, stream>>>(rec, filt, partners, pairs_i, out, n, nwords);
    } else {
        const int block = 256;
        int grid = (n + block - 1) / block;
        if (grid > 2048) grid = 2048;
        electro_fallback<<<grid, block, 0, stream>>>(coords, partners, props,
                                                     desc, (const int2*)pairs_i, out, n);
    }
}

// Round 11
// 30.481 us; speedup vs baseline: 24.6708x; 1.0862x over previous
//
#include <hip/hip_runtime.h>
#include <math.h>

namespace {
constexpr int   NTYPES   = 200;
constexpr float RAD10_   = 0.17453292519943295f;
constexpr float RAD30_   = 0.52359877559829882f;
constexpr float RAD150_  = 2.6179938779914944f;
constexpr float RAD180_  = 3.14159265358979323f;
constexpr float CONST_T  = 0.89776110649108887f; // exp(-0.004314*25)

// folded: 332/(8.8*CONST_T), 0.5*332/(88*CONST_T), sqrt(200*0.05/298),
// vk(|c2e|=1)=sqrt(200*ION_CORR/298), vk(0.5)
constexpr float ARG_K   = 42.0237329f;
constexpr float KON_K   = 2.10118664f;
constexpr float KON_SQK = 0.18318583f;
constexpr float VK_AA   = 0.19337050f;
constexpr float VK_MIX  = 0.13673360f;

// rec.w bits: 0..7 at_name, 8..9 chain, 10..18 resnum,
// 19 rc, 20 cz, 21 aa, 22 charged, 23 virtual, 24 dipole0,
// 25 chg_mag (|c|==1), 26 chg_sign (c<0)
constexpr unsigned RC_B   = 1u << 19;
constexpr unsigned CZ_B   = 1u << 20;
constexpr unsigned AA_B   = 1u << 21;
constexpr unsigned CHG_B  = 1u << 22;
constexpr unsigned VIRT_B = 1u << 23;
constexpr unsigned DIP0_B = 1u << 24;
constexpr unsigned MAG_B  = 1u << 25;
constexpr unsigned SGN_B  = 1u << 26;
constexpr unsigned RESCH_M = 0x7FF00u;
constexpr unsigned CHAIN_M = 0x300u;

constexpr int MAX_FILT_WORDS = 3200;   // 102,400 atoms @ 1 bit/atom
}

typedef int   i4v __attribute__((ext_vector_type(4)));
typedef float f2v __attribute__((ext_vector_type(2)));

// Merged prep: 16 B record + 1-bit filter via ballot, one kernel.
// rec[i] = {x, y, z, bits}; charge/radius folded into bits (radius is dead
// code: sum_radii<=4.31 -> tk==max(dist+dist^2/30, 6) always).
__global__ __launch_bounds__(256) void prep_all(
    const float* __restrict__ coords,
    const float* __restrict__ props,
    const int*   __restrict__ desc,
    float4*      __restrict__ rec,
    unsigned*    __restrict__ filt,
    int nwords, int natoms)
{
    const int idx = blockIdx.x * blockDim.x + threadIdx.x;
    bool interesting = false;
    if (idx < natoms) {
        const int at  = desc[3 * idx];
        const int res = desc[3 * idx + 1];
        const int ch  = desc[3 * idx + 2];
        unsigned bits = (unsigned)at | ((unsigned)ch << 8) | ((unsigned)res << 10);
        if ((at == 10) | (at == 11))       bits |= RC_B;
        if (at == 12)                      bits |= CZ_B;
        if (at == 13)                      bits |= AA_B;
        const float c = props[5 * at + 1];
        if (props[5 * at + 0] == 1.0f)     bits |= CHG_B;
        if (props[5 * at + 2] == 1.0f)     bits |= VIRT_B;
        if (props[5 * at + 3] == 0.0f)     bits |= DIP0_B;
        if (fabsf(c) == 1.0f)              bits |= MAG_B;
        if (c < 0.0f)                      bits |= SGN_B;
        rec[idx] = make_float4(coords[3 * idx], coords[3 * idx + 1],
                               coords[3 * idx + 2], __uint_as_float(bits));
        interesting = ((bits & CHG_B) != 0) | ((bits & (CZ_B | RC_B)) != 0);
    }
    const unsigned long long m = __ballot(interesting);
    const unsigned lane = threadIdx.x & 63u;
    if ((lane & 31u) == 0u) {
        const int w = idx >> 5;
        if (w < nwords) filt[w] = (unsigned)(m >> lane);
    }
}

// Everything needed is in two 16 B records (registers). Only the rare ARG
// path touches memory (partners gathers, usually whole-wave execz).
__device__ __forceinline__ float pe(
    const float4 A, const float4 B, int i, int j,
    const float* __restrict__ partners)
{
    const unsigned ba = __float_as_uint(A.w);
    const unsigned bb = __float_as_uint(B.w);

    const float dx = A.x - B.x, dy = A.y - B.y, dz = A.z - B.z;
    const float dist = sqrtf(dx * dx + dy * dy + dz * dz + 1e-12f);
    const bool diff_res = ((ba ^ bb) & RESCH_M) != 0;
    if (!((dist <= 15.0f) & diff_res)) return 0.0f;

    float energy = 0.0f;

    const bool czA = (ba & CZ_B) != 0, czB = (bb & CZ_B) != 0;
    const bool rcA = (ba & RC_B) != 0, rcB = (bb & RC_B) != 0;
    const bool argInv = (czA & (czB | rcB)) | (czB & (czA | rcA));
    if (argInv && (dist >= 3.9f) && (dist <= 4.3f)) {
        const float a0x = partners[6 * i],     a0y = partners[6 * i + 1], a0z = partners[6 * i + 2];
        const float a1x = partners[6 * i + 3], a1y = partners[6 * i + 4], a1z = partners[6 * i + 5];
        const float b0x = partners[6 * j],     b0y = partners[6 * j + 1], b0z = partners[6 * j + 2];
        const float b1x = partners[6 * j + 3], b1y = partners[6 * j + 4], b1z = partners[6 * j + 5];
        const float u1x = a0x - A.x, u1y = a0y - A.y, u1z = a0z - A.z;
        const float v1x = a1x - A.x, v1y = a1y - A.y, v1z = a1z - A.z;
        const float n1x = u1y * v1z - u1z * v1y;
        const float n1y = u1z * v1x - u1x * v1z;
        const float n1z = u1x * v1y - u1y * v1x;
        const float u2x = b0x - B.x, u2y = b0y - B.y, u2z = b0z - B.z;
        const float v2x = b1x - B.x, v2y = b1y - B.y, v2z = b1z - B.z;
        const float n2x = u2y * v2z - u2z * v2y;
        const float n2y = u2z * v2x - u2x * v2z;
        const float n2z = u2x * v2y - u2y * v2x;
        const float nn1 = sqrtf(n1x * n1x + n1y * n1y + n1z * n1z + 1e-12f);
        const float nn2 = sqrtf(n2x * n2x + n2y * n2y + n2z * n2z + 1e-12f);
        const bool  m = (nn1 > 1e-6f) & (nn2 > 1e-6f);
        float cosang = (n1x * n2x + n1y * n2y + n1z * n2z) / (nn1 * nn2);
        cosang = fminf(fmaxf(cosang, -0.999999f), 0.999999f);
        const float ang = acosf(cosang);
        const bool ang_mid_bad = (ang > RAD30_) & (ang < RAD150_);
        if (m & !ang_mid_bad) {
            const float temp_d = 3.0f + fabsf(dist - 4.1f);
            // dist in [3.9,4.3] > RAD150 -> angle-corr branch always
            const float corr = fmaxf((RAD180_ - ang) * (1.0f / RAD10_), 1.0f);
            const bool  arg_arg = ((ba & bb & AA_B) != 0);
            const float c2e = arg_arg ? -1.0f : -0.5f;
            const float vk  = arg_arg ? VK_AA : VK_MIX;
            energy += c2e * ARG_K * expf(-temp_d * vk) /
                      (corr * dist * temp_d * temp_d);
        }
    }

    // kon: charge magnitude/sign from bits (c != 0 <=> CHG flag; radius dead)
    const bool kon = ((ba & bb & CHG_B) != 0) &
                     (((ba | bb) & VIRT_B) == 0) &
                     ((ba & bb & DIP0_B) != 0) &
                     (((ba ^ bb) & CHAIN_M) != 0);
    if (kon) {
        const float tk = fmaxf(dist + dist * dist * (1.0f / 30.0f), 6.0f);
        const int ms = (int)((ba >> 25) & 1u) + (int)((bb >> 25) & 1u);
        const float mag  = (ms == 0) ? 0.25f : ((ms == 1) ? 0.5f : 1.0f);
        const float k_on = KON_SQK * ((ms == 0) ? 0.5f : ((ms == 1) ? 0.70710678f : 1.0f));
        const float e = KON_K * mag * expf(-k_on * (tk - 6.0f)) /
                        (tk * (1.0f + 6.0f * k_on));
        energy += (((ba ^ bb) & SGN_B) != 0) ? -e : e;
    }
    return energy;
}

// Persistent-block version: LDS filter staged ONCE per block (uint4), then
// grid-stride loop over 512-pair tiles with software-pipelined pair loads.
// NT hints on the read-once pairs stream and write-once out stream keep
// L2 for the rec table.
__global__ __launch_bounds__(256, 6) void electro_k11(
    const float4*   __restrict__ rec,       // [natoms] 1.6 MB, L2-resident
    const unsigned* __restrict__ filtg,     // [nwords] 12.5 KB -> LDS
    const float*    __restrict__ partners,
    const int*      __restrict__ pairs_raw,
    float*          __restrict__ out,
    int n, int nwords, int tiles)
{
    __shared__ unsigned sfilt[MAX_FILT_WORDS];
    {
        const uint4* fsrc = reinterpret_cast<const uint4*>(filtg);
        const int nv = nwords >> 2;
        for (int t = threadIdx.x; t < nv; t += 256) {
            const uint4 v = fsrc[t];
            sfilt[4 * t]     = v.x;  sfilt[4 * t + 1] = v.y;
            sfilt[4 * t + 2] = v.z;  sfilt[4 * t + 3] = v.w;
        }
        for (int t = (nv << 2) + threadIdx.x; t < nwords; t += 256)
            sfilt[t] = filtg[t];
    }
    __syncthreads();

    const int tid = (int)threadIdx.x;

    auto load_tile = [&](int tile) -> i4v {
        const int p = (tile << 9) + 2 * tid;
        if (p + 1 < n)
            return __builtin_nontemporal_load(
                reinterpret_cast<const i4v*>(pairs_raw + 2 * p));
        i4v r = (i4v)0;
        if (p < n) { r.x = pairs_raw[2 * p]; r.y = pairs_raw[2 * p + 1]; }
        return r;
    };

    int tile = blockIdx.x;
    if (tile >= tiles) return;
    i4v cur = load_tile(tile);

    while (true) {
        const int next = tile + gridDim.x;
        i4v nxt = (i4v)0;
        if (next < tiles) nxt = load_tile(next);   // prefetch: hides under current tile

        const int p0 = (tile << 9) + 2 * tid;      // pairs p0, p0+1
        const int i0 = cur.x, j0 = cur.y, i1 = cur.z, j1 = cur.w;

        const bool f0 = (((sfilt[i0 >> 5] >> (i0 & 31)) & (sfilt[j0 >> 5] >> (j0 & 31))) & 1u) != 0;
        const bool f1 = (((sfilt[i1 >> 5] >> (i1 & 31)) & (sfilt[j1 >> 5] >> (j1 & 31))) & 1u) != 0;

        // select-to-zero: failing lanes broadcast line 0 (free)
        const int a0 = f0 ? i0 : 0, b0 = f0 ? j0 : 0;
        const int a1 = f1 ? i1 : 0, b1 = f1 ? j1 : 0;

        const float4 A0 = rec[a0];
        const float4 B0 = rec[b0];
        const float4 A1 = rec[a1];
        const float4 B1 = rec[b1];

        const float e0 = f0 ? pe(A0, B0, i0, j0, partners) : 0.0f;
        const float e1 = f1 ? pe(A1, B1, i1, j1, partners) : 0.0f;

        if (p0 + 1 < n) {
            f2v r; r.x = e0; r.y = e1;
            __builtin_nontemporal_store(r, reinterpret_cast<f2v*>(out + p0));
        } else if (p0 < n) {
            out[p0] = e0;
        }

        if (next >= tiles) break;
        tile = next;
        cur  = nxt;
    }
}

// -------- fallback (reference-direct) if d_ws too small / atoms too many --------
__global__ __launch_bounds__(256) void electro_fallback(
    const float* __restrict__ coords, const float* __restrict__ partners,
    const float* __restrict__ props, const int* __restrict__ desc,
    const int2* __restrict__ pairs, float* __restrict__ out, int n)
{
    __shared__ float sp[NTYPES * 5];
    for (int t = threadIdx.x; t < NTYPES * 5; t += blockDim.x) sp[t] = props[t];
    __syncthreads();
    const int stride = gridDim.x * blockDim.x;
    for (int p = blockIdx.x * blockDim.x + threadIdx.x; p < n; p += stride) {
        const int2 ij = pairs[p];
        const int i = ij.x, j = ij.y;
        const int at1 = desc[3 * i], at2 = desc[3 * j];
        const bool rc1 = (at1 == 10) | (at1 == 11);
        const bool rc2 = (at2 == 10) | (at2 == 11);
        const bool argInv = ((at1 == 12) & ((at2 == 12) | rc2)) |
                            ((at2 == 12) & ((at1 == 12) | rc1));
        const float* p1 = &sp[5 * at1];
        const float* p2 = &sp[5 * at2];
        const bool is_charged = ((p1[0] == 1.0f) & (p2[0] == 1.0f)) | argInv;
        float energy = 0.0f;
        if (is_charged) {
            const int res1 = desc[3 * i + 1], ch1 = desc[3 * i + 2];
            const int res2 = desc[3 * j + 1], ch2 = desc[3 * j + 2];
            const float ax = coords[3 * i], ay = coords[3 * i + 1], az = coords[3 * i + 2];
            const float bx = coords[3 * j], by = coords[3 * j + 1], bz = coords[3 * j + 2];
            const float dx = ax - bx, dy = ay - by, dz = az - bz;
            const float dist = sqrtf(dx * dx + dy * dy + dz * dz + 1e-12f);
            const bool diff_res = (res1 != res2) | (ch1 != ch2);
            if ((dist <= 15.0f) & diff_res) {
                if (argInv && (dist >= 3.9f) && (dist <= 4.3f)) {
                    const float a0x = partners[6*i],   a0y = partners[6*i+1], a0z = partners[6*i+2];
                    const float a1x = partners[6*i+3], a1y = partners[6*i+4], a1z = partners[6*i+5];
                    const float b0x = partners[6*j],   b0y = partners[6*j+1], b0z = partners[6*j+2];
                    const float b1x = partners[6*j+3], b1y = partners[6*j+4], b1z = partners[6*j+5];
                    const float u1x=a0x-ax,u1y=a0y-ay,u1z=a0z-az;
                    const float v1x=a1x-ax,v1y=a1y-ay,v1z=a1z-az;
                    const float n1x=u1y*v1z-u1z*v1y, n1y=u1z*v1x-u1x*v1z, n1z=u1x*v1y-u1y*v1x;
                    const float u2x=b0x-bx,u2y=b0y-by,u2z=b0z-bz;
                    const float v2x=b1x-bx,v2y=b1y-by,v2z=b1z-bz;
                    const float n2x=u2y*v2z-u2z*v2y, n2y=u2z*v2x-u2x*v2z, n2z=u2x*v2y-u2y*v2x;
                    const float nn1 = sqrtf(n1x*n1x+n1y*n1y+n1z*n1z+1e-12f);
                    const float nn2 = sqrtf(n2x*n2x+n2y*n2y+n2z*n2z+1e-12f);
                    const bool m = (nn1 > 1e-6f) & (nn2 > 1e-6f);
                    float cosang = (n1x*n2x+n1y*n2y+n1z*n2z)/(nn1*nn2);
                    cosang = fminf(fmaxf(cosang, -0.999999f), 0.999999f);
                    const float ang = acosf(cosang);
                    const bool ang_mid_bad = (ang > RAD30_) & (ang < RAD150_);
                    if (m & !ang_mid_bad) {
                        const float dsafe = fmaxf(dist, 1e-6f);
                        const float argEpss = 332.0f / (dsafe * 8.8f * CONST_T);
                        const float temp_d = 3.0f + fabsf(dist - 4.1f);
                        const float corr_ang = (dist > RAD150_)
                            ? fmaxf((RAD180_ - ang) / RAD10_, 1.0f)
                            : fmaxf(dist / RAD10_, 1.0f);
                        const bool arg_arg = (at1 == 13) & (at2 == 13);
                        const float c2e = arg_arg ? -1.0f : -0.5f;
                        const float vk = sqrtf(200.0f * fabsf(c2e) * (0.02f + 0.05f/1.4f) / 298.0f);
                        energy += (1.0f/corr_ang)*c2e*argEpss*expf(-temp_d*vk)/(temp_d*temp_d);
                    }
                }
                const float c1 = p1[1], c2 = p2[1];
                const bool cc = (c1 != 0.0f) & (c2 != 0.0f) &
                                (p1[2] != 1.0f) & (p2[2] != 1.0f);
                const bool kon_mask = cc & (p1[3] == 0.0f) & (p2[3] == 0.0f) & (ch1 != ch2);
                if (kon_mask) {
                    const float sum_radii = p1[4] + p2[4] - 0.09f;
                    const float dd = fmaxf(dist, sum_radii);
                    const float tk = fmaxf(dd + dd*dd*(1.0f/30.0f), 6.0f);
                    const float k_on = sqrtf(200.0f*fabsf(c1)*fabsf(c2)*0.05f/298.0f);
                    const float first = 332.0f*c1*c2/(88.0f*tk*CONST_T);
                    const float second = expf(-k_on*(tk-6.0f));
                    const float third = 1.0f + k_on*6.0f;
                    energy += 0.5f*first*second/third;
                }
            }
        }
        out[p] = energy;
    }
}

extern "C" void kernel_launch(void* const* d_in, const int* in_sizes, int n_in,
                              void* d_out, int out_size, void* d_ws, size_t ws_size,
                              hipStream_t stream) {
    const float* coords   = (const float*)d_in[0];
    const float* partners = (const float*)d_in[1];
    const float* props    = (const float*)d_in[2];
    const int*   desc     = (const int*)d_in[3];
    const int*   pairs_i  = (const int*)d_in[4];
    float*       out      = (float*)d_out;

    const int natoms = in_sizes[0] / 3;    // 100,000
    const int n      = in_sizes[4] / 2;    // 4,000,000 pairs
    const int nwords = (natoms + 31) / 32; // 3,125

    const size_t rec_bytes  = (size_t)natoms * sizeof(float4);
    const size_t filt_off   = (rec_bytes + 255) & ~(size_t)255;
    const size_t need_bytes = filt_off + (size_t)nwords * sizeof(unsigned);

    if (ws_size >= need_bytes && nwords <= MAX_FILT_WORDS) {
        float4*   rec  = (float4*)d_ws;
        unsigned* filt = (unsigned*)((char*)d_ws + filt_off);
        prep_all<<<(natoms + 255) / 256, 256, 0, stream>>>(
            coords, props, desc, rec, filt, nwords, natoms);
        const int tiles = (n + 511) / 512;             // 512 pairs per tile
        int grid = tiles < 2560 ? tiles : 2560;        // persistent blocks, ~10/CU queued
        electro_k11<<<grid, 256, 0, stream>>>(rec, filt, partners, pairs_i,
                                              out, n, nwords, tiles);
    } else {
        const int block = 256;
        int grid = (n + block - 1) / block;
        if (grid > 2048) grid = 2048;
        electro_fallback<<<grid, block, 0, stream>>>(coords, partners, props,
                                                     desc, (const int2*)pairs_i, out, n);
    }
}